// Round 16
// baseline (124.031 us; speedup 1.0000x reference)
//
#include <hip/hip_runtime.h>
#include <hip/hip_bf16.h>

#define N_NODES 50000
#define KNN     16
#define NEDGE   (N_NODES*KNN)     // 800000
#define NTILE2  (NEDGE/128)       // 6250 tiles of 128 edges (8 nodes)  -> kS3
#define NTILE4  (NEDGE/256)       // 3125 tiles of 256 edges (16 nodes) -> kS1/kS2
#define NWT     (N_NODES/16)      // 3125 wave-tiles for kUV
#define NB2     1024              // grid kS1/kS2/kS3
#define SLOPE   0.01f
#define EPS     1e-5f

typedef __attribute__((ext_vector_type(8))) short bf16x8;
typedef __attribute__((ext_vector_type(4))) float f32x4;

__device__ __forceinline__ float bfbits(unsigned u){ union{unsigned u;float f;}v; v.u=u; return v.f; }
__device__ __forceinline__ unsigned fbits(float f){ union{float f;unsigned u;}v; v.f=f; return v.u; }
__device__ __forceinline__ unsigned pk2(float a, float b){
  const unsigned ua = fbits(a) + 0x8000u;
  const unsigned ub = fbits(b) + 0x8000u;
  return __builtin_amdgcn_perm(ub, ua, 0x07060302u);
}
__device__ __forceinline__ unsigned short f2bfr(float f){
  return (unsigned short)((fbits(f) + 0x8000u) >> 16);
}
__device__ __forceinline__ bf16x8 asfrag(uint4 u){ union{uint4 v; bf16x8 b;}q; q.v=u; return q.b; }
__device__ __forceinline__ f32x4 MFMA(bf16x8 a, bf16x8 b, f32x4 c){
  return __builtin_amdgcn_mfma_f32_16x16x32_bf16(a, b, c, 0, 0, 0);
}
__device__ __forceinline__ float lrelu(float v){ return v>=0.f ? v : SLOPE*v; }

__device__ __forceinline__ void unp8(bf16x8 v, float* o){
  union{bf16x8 b; unsigned u[4];}q; q.b=v;
#pragma unroll
  for (int w=0;w<4;++w){
    o[2*w]   = bfbits(q.u[w]<<16);
    o[2*w+1] = bfbits(q.u[w]&0xffff0000u);
  }
}
__device__ __forceinline__ bf16x8 pack8r(const float* f){
  union{unsigned u[4]; bf16x8 b;}q;
#pragma unroll
  for (int i=0;i<4;++i) q.u[i] = pk2(f[2*i], f[2*i+1]);
  return q.b;
}
__device__ __forceinline__ bf16x8 pack8v(float4 a, float4 b){
  union{unsigned u[4]; bf16x8 v;}q;
  q.u[0]=pk2(a.x,a.y); q.u[1]=pk2(a.z,a.w);
  q.u[2]=pk2(b.x,b.y); q.u[3]=pk2(b.z,b.w);
  return q.v;
}

// ---- kInit: pack W frags. W1 folded: frags 0..7 = A-B, 8..15 = B -----------
__global__ __launch_bounds__(256) void kInit(const float* __restrict__ W1,
    const float* __restrict__ W2, const float* __restrict__ W3,
    unsigned short* __restrict__ wf)
{
  const int idx = blockIdx.x*256 + threadIdx.x;   // 2048 entries
  const float* W; int fi; bool fold = false;
  if (idx < 1024)      { W = W1; fi = idx >> 6; fold = (idx < 512); }
  else if (idx < 1536) { W = W2; fi = (idx-1024) >> 6; }
  else                 { W = W3; fi = (idx-1536) >> 6; }
  const int l  = idx & 63;
  const int ks = fi >> 2, nf = fi & 3;
  const int k0 = ks*32 + ((l>>4)<<3);
  const int col = nf*16 + (l&15);
  unsigned short* o = wf + (size_t)idx*8;
#pragma unroll
  for (int e=0;e<8;++e){
    float v = W[(size_t)(k0+e)*64 + col];
    if (fold) v -= W[(size_t)(k0+e+64)*64 + col];
    o[e] = f2bfr(v);
  }
}

// ---- kUV: per-node U = x(A-B), V = xB (bf16) -------------------------------
__global__ __launch_bounds__(256) void kUV(const float* __restrict__ x,
    const uint4* __restrict__ wf, unsigned short* __restrict__ Ub,
    unsigned short* __restrict__ Vb)
{
  const int t = threadIdx.x, w = t>>6, l = t&63, lr = l&15, lg = l>>4;
  const int wt = blockIdx.x*4 + w;
  if (wt >= NWT) return;
  bf16x8 wfr[16];
#pragma unroll
  for (int f=0;f<16;++f) wfr[f] = asfrag(wf[f*64 + l]);
  const int n0 = wt*16;
  const float* xr = x + (size_t)(n0+lr)*64 + lg*8;
  const bf16x8 a0 = pack8v(((const float4*)xr)[0],      ((const float4*)xr)[1]);
  const bf16x8 a1 = pack8v(((const float4*)(xr+32))[0], ((const float4*)(xr+32))[1]);

  f32x4 aU[4], aV[4];
#pragma unroll
  for (int nf=0;nf<4;++nf){
    aU[nf] = (f32x4){0,0,0,0};
    aU[nf] = MFMA(a0, wfr[nf],    aU[nf]);
    aU[nf] = MFMA(a1, wfr[4+nf],  aU[nf]);
    aV[nf] = (f32x4){0,0,0,0};
    aV[nf] = MFMA(a0, wfr[8+nf],  aV[nf]);
    aV[nf] = MFMA(a1, wfr[12+nf], aV[nf]);
  }
#pragma unroll
  for (int nf=0;nf<4;++nf)
#pragma unroll
    for (int r=0;r<4;++r){
      const size_t o = (size_t)(n0 + 4*lg + r)*64 + 16*nf + lr;
      Ub[o] = f2bfr(aU[nf][r]);
      Vb[o] = f2bfr(aV[nf][r]);
    }
}

#define LOADUV(U0,U1,V0,V1, nodeId, srcId)                               \
  {                                                                      \
    const unsigned short* Ur = Ub + (size_t)(nodeId)*64 + lg*8;          \
    const unsigned short* Vr = Vb + (size_t)(srcId)*64  + lg*8;          \
    U0 = *(const bf16x8*)(Ur); U1 = *(const bf16x8*)(Ur + 32);           \
    V0 = *(const bf16x8*)(Vr); V1 = *(const bf16x8*)(Vr + 32);           \
  }

#define H1COMP(h0f, h1f, U0,U1,V0,V1)                                   \
  bf16x8 h0f, h1f;                                                      \
  {                                                                     \
    float fu[8], fv[8], h[8];                                           \
    unp8(U0,fu); unp8(V0,fv);                                           \
    _Pragma("unroll")                                                   \
    for (int e=0;e<8;++e) h[e] = lrelu(fu[e]+fv[e]);                    \
    h0f = pack8r(h);                                                    \
    unp8(U1,fu); unp8(V1,fv);                                           \
    _Pragma("unroll")                                                   \
    for (int e=0;e<8;++e) h[e] = lrelu(fu[e]+fv[e]);                    \
    h1f = pack8r(h);                                                    \
  }

// accumulate stats of z = U + V for one stream (two 8-ch halves)
#define ACCST(U0,U1,V0,V1)                                              \
  {                                                                     \
    float fu[8], fv[8];                                                 \
    unp8(U0,fu); unp8(V0,fv);                                           \
    _Pragma("unroll")                                                   \
    for (int e=0;e<8;++e){ const float z = fu[e]+fv[e]; s[e]+=z; q[e]=fmaf(z,z,q[e]); } \
    unp8(U1,fu); unp8(V1,fv);                                           \
    _Pragma("unroll")                                                   \
    for (int e=0;e<8;++e){ const float z = fu[e]+fv[e]; s[8+e]+=z; q[8+e]=fmaf(z,z,q[8+e]); } \
  }

// ---- kS1: 4-node ILP; stats of z1 = U[dst] + V[src] (no MFMA) --------------
__global__ __launch_bounds__(256,4) void kS1(const unsigned short* __restrict__ Ub,
    const unsigned short* __restrict__ Vb, const int* __restrict__ ei,
    float* __restrict__ part)
{
  __shared__ float red[4][128];
  const int t = threadIdx.x, w = t>>6, l = t&63, lr = l&15, lg = l>>4;
  const int G = gridDim.x;

  float s[16], q[16];
#pragma unroll
  for (int k=0;k<16;++k){ s[k]=0.f; q[k]=0.f; }

  int tile = blockIdx.x;
  int sA = ei[tile*256 + (4*w+0)*16 + lr];
  int sB = ei[tile*256 + (4*w+1)*16 + lr];
  int sC = ei[tile*256 + (4*w+2)*16 + lr];
  int sD = ei[tile*256 + (4*w+3)*16 + lr];
  for (; tile < NTILE4; tile += G){
    const int n0 = tile*16 + 4*w;
    bf16x8 uA0,uA1,vA0,vA1, uB0,uB1,vB0,vB1;
    bf16x8 uC0,uC1,vC0,vC1, uD0,uD1,vD0,vD1;
    LOADUV(uA0,uA1,vA0,vA1, n0+0, sA)
    LOADUV(uB0,uB1,vB0,vB1, n0+1, sB)
    LOADUV(uC0,uC1,vC0,vC1, n0+2, sC)
    LOADUV(uD0,uD1,vD0,vD1, n0+3, sD)
    const int nt = tile + G;
    if (nt < NTILE4){
      sA = ei[nt*256 + (4*w+0)*16 + lr];
      sB = ei[nt*256 + (4*w+1)*16 + lr];
      sC = ei[nt*256 + (4*w+2)*16 + lr];
      sD = ei[nt*256 + (4*w+3)*16 + lr];
    }
    ACCST(uA0,uA1,vA0,vA1)
    ACCST(uB0,uB1,vB0,vB1)
    ACCST(uC0,uC1,vC0,vC1)
    ACCST(uD0,uD1,vD0,vD1)
  }

#pragma unroll
  for (int k=0;k<16;++k){
    float a=s[k]; a+=__shfl_xor(a,1,64); a+=__shfl_xor(a,2,64);
    a+=__shfl_xor(a,4,64); a+=__shfl_xor(a,8,64); s[k]=a;
    float b=q[k]; b+=__shfl_xor(b,1,64); b+=__shfl_xor(b,2,64);
    b+=__shfl_xor(b,4,64); b+=__shfl_xor(b,8,64); q[k]=b;
  }
  if (lr == 0){
#pragma unroll
    for (int e=0;e<8;++e){
      red[w][8*lg+e]    = s[e];
      red[w][32+8*lg+e] = s[8+e];
      red[w][64+8*lg+e] = q[e];
      red[w][96+8*lg+e] = q[8+e];
    }
  }
  __syncthreads();
  if (t < 128)
    part[(size_t)t*NB2 + blockIdx.x] = red[0][t]+red[1][t]+red[2][t]+red[3][t];
}

// ---- kFin: 64 blocks, block c reduces sum/sq rows over nb entries ----------
__global__ __launch_bounds__(256) void kFin(const float* __restrict__ part,
    const float* __restrict__ g, const float* __restrict__ be,
    float* __restrict__ coefs, int nb)
{
  __shared__ float rs[256], rq[256];
  const int c = blockIdx.x, t = threadIdx.x;
  const float* ps = part + (size_t)c*nb;
  const float* pq = part + (size_t)(64+c)*nb;
  float s = 0.f, q = 0.f;
  for (int i=t; i<nb; i+=256){ s += ps[i]; q += pq[i]; }
  rs[t]=s; rq[t]=q;
  __syncthreads();
#pragma unroll
  for (int off=128; off>0; off>>=1){
    if (t < off){ rs[t]+=rs[t+off]; rq[t]+=rq[t+off]; }
    __syncthreads();
  }
  if (t==0){
    const float inv  = 1.0f/(float)NEDGE;
    const float mean = rs[0]*inv;
    const float var  = rq[0]*inv - mean*mean;
    const float a    = g[c]*rsqrtf(var + EPS);
    coefs[c]      = a;
    coefs[64 + c] = be[c] - mean*a;
  }
}

// ---- kScale: U' = a*U + c ; V' = a*V (in place, fold BN1) ------------------
__global__ __launch_bounds__(256) void kScale(unsigned short* __restrict__ Ub,
    unsigned short* __restrict__ Vb, const float* __restrict__ coefs)
{
  const int j = blockIdx.x*256 + threadIdx.x;
  if (j >= N_NODES*8) return;
  const int c0 = (j & 7)*8;
  float a[8], c[8], f[8];
#pragma unroll
  for (int e=0;e<8;++e){ a[e]=coefs[c0+e]; c[e]=coefs[64+c0+e]; }
  bf16x8 u = ((const bf16x8*)Ub)[j];
  unp8(u,f);
#pragma unroll
  for (int e=0;e<8;++e) f[e] = fmaf(a[e], f[e], c[e]);
  ((bf16x8*)Ub)[j] = pack8r(f);
  bf16x8 v = ((const bf16x8*)Vb)[j];
  unp8(v,f);
#pragma unroll
  for (int e=0;e<8;++e) f[e] *= a[e];
  ((bf16x8*)Vb)[j] = pack8r(f);
}

// ---- kS2: 4-node ILP; h1 = lrelu(U'+V'); z2 = h1@W2; stats2 ----------------
__global__ __launch_bounds__(256,4) void kS2(const unsigned short* __restrict__ Ub,
    const unsigned short* __restrict__ Vb, const int* __restrict__ ei,
    const uint4* __restrict__ wfg, float* __restrict__ part)
{
  __shared__ uint4 wlds[512];          // wf2 table, 8 KB
  __shared__ float red[4][128];
  const int t = threadIdx.x, w = t>>6, l = t&63, lr = l&15, lg = l>>4;
  const int G = gridDim.x;
  const f32x4 Z4 = (f32x4){0.f,0.f,0.f,0.f};

  for (int i=t; i<512; i+=256) wlds[i] = wfg[1024+i];
  __syncthreads();

  float sumP[4] = {0,0,0,0}, sqP[4] = {0,0,0,0};

  int tile = blockIdx.x;
  int sA = ei[tile*256 + (4*w+0)*16 + lr];
  int sB = ei[tile*256 + (4*w+1)*16 + lr];
  int sC = ei[tile*256 + (4*w+2)*16 + lr];
  int sD = ei[tile*256 + (4*w+3)*16 + lr];
  for (; tile < NTILE4; tile += G){
    const int n0 = tile*16 + 4*w;
    bf16x8 uA0,uA1,vA0,vA1, uB0,uB1,vB0,vB1;
    bf16x8 uC0,uC1,vC0,vC1, uD0,uD1,vD0,vD1;
    LOADUV(uA0,uA1,vA0,vA1, n0+0, sA)
    LOADUV(uB0,uB1,vB0,vB1, n0+1, sB)
    LOADUV(uC0,uC1,vC0,vC1, n0+2, sC)
    LOADUV(uD0,uD1,vD0,vD1, n0+3, sD)
    const int nt = tile + G;
    if (nt < NTILE4){
      sA = ei[nt*256 + (4*w+0)*16 + lr];
      sB = ei[nt*256 + (4*w+1)*16 + lr];
      sC = ei[nt*256 + (4*w+2)*16 + lr];
      sD = ei[nt*256 + (4*w+3)*16 + lr];
    }

    H1COMP(hA0, hA1, uA0,uA1,vA0,vA1)
    H1COMP(hB0, hB1, uB0,uB1,vB0,vB1)
    H1COMP(hC0, hC1, uC0,uC1,vC0,vC1)
    H1COMP(hD0, hD1, uD0,uD1,vD0,vD1)

    f32x4 aA[4], aB[4], aC[4], aD[4];
#pragma unroll
    for (int nf=0;nf<4;++nf){
      const bf16x8 b0 = asfrag(wlds[nf*64 + l]);
      const bf16x8 b1 = asfrag(wlds[(4+nf)*64 + l]);
      aA[nf] = MFMA(hA0, b0, Z4);  aA[nf] = MFMA(hA1, b1, aA[nf]);
      aB[nf] = MFMA(hB0, b0, Z4);  aB[nf] = MFMA(hB1, b1, aB[nf]);
      aC[nf] = MFMA(hC0, b0, Z4);  aC[nf] = MFMA(hC1, b1, aC[nf]);
      aD[nf] = MFMA(hD0, b0, Z4);  aD[nf] = MFMA(hD1, b1, aD[nf]);
    }
#pragma unroll
    for (int nf=0;nf<4;++nf)
#pragma unroll
      for (int r=0;r<4;++r){
        const float v0 = aA[nf][r], v1 = aB[nf][r];
        const float v2 = aC[nf][r], v3 = aD[nf][r];
        sumP[nf] += (v0 + v1) + (v2 + v3);
        sqP[nf] = fmaf(v0,v0,sqP[nf]);
        sqP[nf] = fmaf(v1,v1,sqP[nf]);
        sqP[nf] = fmaf(v2,v2,sqP[nf]);
        sqP[nf] = fmaf(v3,v3,sqP[nf]);
      }
  }

#pragma unroll
  for (int nf=0;nf<4;++nf){
    float s = sumP[nf], q = sqP[nf];
    s += __shfl_xor(s,16,64); s += __shfl_xor(s,32,64);
    q += __shfl_xor(q,16,64); q += __shfl_xor(q,32,64);
    if (l < 16){ red[w][nf*16+l] = s; red[w][64+nf*16+l] = q; }
  }
  __syncthreads();
  if (t < 128)
    part[(size_t)t*NB2 + blockIdx.x] = red[0][t]+red[1][t]+red[2][t]+red[3][t];
}

// ---- kS3: 2-node ILP; h1 -> z2 -> BN2+lrelu -> z3 -> segmax -> out ---------
__global__ __launch_bounds__(256,4) void kS3(const unsigned short* __restrict__ Ub,
    const unsigned short* __restrict__ Vb, const int* __restrict__ ei,
    const uint4* __restrict__ wfg, const float* __restrict__ coefs2,
    const float* __restrict__ b3, const float* __restrict__ x,
    float* __restrict__ out)
{
  __shared__ uint4 wlds[1024];                              // wf2|wf3, 16 KB
  __shared__ __align__(16) unsigned short buf[8][16][72];   // per-stream, 18 KB
  const int t = threadIdx.x, w = t>>6, l = t&63, lr = l&15, lg = l>>4;
  const int G = gridDim.x;
  const f32x4 Z4 = (f32x4){0.f,0.f,0.f,0.f};

  for (int i=t; i<1024; i+=256) wlds[i] = wfg[1024+i];
  __syncthreads();

  float a2v[4], c2v[4], bb[4];
#pragma unroll
  for (int nf=0;nf<4;++nf){
    a2v[nf]=coefs2[nf*16+lr]; c2v[nf]=coefs2[64+nf*16+lr];
    bb[nf] = b3[nf*16+lr];
  }

  int tile = blockIdx.x;
  int srcA = ei[tile*128 + (2*w)*16 + lr];
  int srcB = ei[tile*128 + (2*w+1)*16 + lr];
  for (; tile < NTILE2; tile += G){
    const int nA = tile*8 + 2*w, nB = nA + 1;
    bf16x8 uA0,uA1,vA0,vA1, uB0,uB1,vB0,vB1;
    LOADUV(uA0,uA1,vA0,vA1, nA, srcA)
    LOADUV(uB0,uB1,vB0,vB1, nB, srcB)
    const int nt = tile + G;
    if (nt < NTILE2){
      srcA = ei[nt*128 + (2*w)*16 + lr];
      srcB = ei[nt*128 + (2*w+1)*16 + lr];
    }

    H1COMP(hA0, hA1, uA0,uA1,vA0,vA1)
    H1COMP(hB0, hB1, uB0,uB1,vB0,vB1)

    // GEMM2 (unswapped): D = z2[edge 4lg+r][ch 16nf+lr]; B shared across streams
    f32x4 aA[4], aB[4];
#pragma unroll
    for (int nf=0;nf<4;++nf){
      const bf16x8 b0 = asfrag(wlds[nf*64 + l]);
      const bf16x8 b1 = asfrag(wlds[(4+nf)*64 + l]);
      aA[nf] = MFMA(hA0, b0, Z4);  aA[nf] = MFMA(hA1, b1, aA[nf]);
      aB[nf] = MFMA(hB0, b0, Z4);  aB[nf] = MFMA(hB1, b1, aB[nf]);
    }
    // BN2 + lrelu -> per-stream transpose buffers
#pragma unroll
    for (int nf=0;nf<4;++nf)
#pragma unroll
      for (int r=0;r<4;++r){
        buf[2*w  ][4*lg+r][16*nf+lr] = f2bfr(lrelu(fmaf(a2v[nf], aA[nf][r], c2v[nf])));
        buf[2*w+1][4*lg+r][16*nf+lr] = f2bfr(lrelu(fmaf(a2v[nf], aB[nf][r], c2v[nf])));
      }
    const bf16x8 gA0 = *(const bf16x8*)&buf[2*w  ][lr][8*lg];
    const bf16x8 gA1 = *(const bf16x8*)&buf[2*w  ][lr][32+8*lg];
    const bf16x8 gB0 = *(const bf16x8*)&buf[2*w+1][lr][8*lg];
    const bf16x8 gB1 = *(const bf16x8*)&buf[2*w+1][lr][32+8*lg];

    f32x4 cA[4], cB[4];
#pragma unroll
    for (int nf=0;nf<4;++nf){
      const bf16x8 b0 = asfrag(wlds[512 + nf*64 + l]);
      const bf16x8 b1 = asfrag(wlds[512 + (4+nf)*64 + l]);
      cA[nf] = MFMA(gA0, b0, Z4);  cA[nf] = MFMA(gA1, b1, cA[nf]);
      cB[nf] = MFMA(gB0, b0, Z4);  cB[nf] = MFMA(gB1, b1, cB[nf]);
    }

    // segmax over each node's 16 edges; bias after max; residual
#pragma unroll
    for (int nf=0;nf<4;++nf){
      float mA = fmaxf(fmaxf(cA[nf][0],cA[nf][1]), fmaxf(cA[nf][2],cA[nf][3]));
      mA = fmaxf(mA, __shfl_xor(mA,16,64));
      mA = fmaxf(mA, __shfl_xor(mA,32,64));
      float mB = fmaxf(fmaxf(cB[nf][0],cB[nf][1]), fmaxf(cB[nf][2],cB[nf][3]));
      mB = fmaxf(mB, __shfl_xor(mB,16,64));
      mB = fmaxf(mB, __shfl_xor(mB,32,64));
      if (l < 16){
        const float xA = x[(size_t)nA*64 + nf*16 + l];
        out[(size_t)nA*64 + nf*16 + l] = lrelu(mA + bb[nf] + xA);
        const float xB = x[(size_t)nB*64 + nf*16 + l];
        out[(size_t)nB*64 + nf*16 + l] = lrelu(mB + bb[nf] + xB);
      }
    }
  }
}

extern "C" void kernel_launch(void* const* d_in, const int* in_sizes, int n_in,
                              void* d_out, int out_size, void* d_ws, size_t ws_size,
                              hipStream_t stream) {
  const float* x   = (const float*)d_in[0];
  const int*   ei  = (const int*)d_in[1];
  const float* W1  = (const float*)d_in[2];
  const float* g1  = (const float*)d_in[4];
  const float* be1 = (const float*)d_in[5];
  const float* W2  = (const float*)d_in[6];
  const float* g2  = (const float*)d_in[8];
  const float* be2 = (const float*)d_in[9];
  const float* W3  = (const float*)d_in[10];
  const float* b3  = (const float*)d_in[11];
  float* out = (float*)d_out;

  // ws: coefs 1KB | part1 512KB | part2 512KB | wfb 32KB | U 6.4MB | V 6.4MB
  float*          coefs = (float*)d_ws;
  float*          part1 = (float*)((char*)d_ws + 1024);
  float*          part2 = part1 + (size_t)NB2*128;
  unsigned short* wfb   = (unsigned short*)((char*)part2 + (size_t)NB2*128*4);
  unsigned short* Ub    = (unsigned short*)((char*)wfb + 32768);
  unsigned short* Vb    = Ub + (size_t)N_NODES*64;

  kInit<<<8, 256, 0, stream>>>(W1, W2, W3, wfb);
  kUV<<<(NWT+3)/4, 256, 0, stream>>>(x, (const uint4*)wfb, Ub, Vb);
  kS1<<<NB2, 256, 0, stream>>>(Ub, Vb, ei, part1);
  kFin<<<64, 256, 0, stream>>>(part1, g1, be1, coefs, NB2);
  kScale<<<(N_NODES*8 + 255)/256, 256, 0, stream>>>(Ub, Vb, coefs);
  kS2<<<NB2, 256, 0, stream>>>(Ub, Vb, ei, (const uint4*)wfb, part2);
  kFin<<<64, 256, 0, stream>>>(part2, g2, be2, coefs + 128, NB2);
  kS3<<<NB2, 256, 0, stream>>>(Ub, Vb, ei, (const uint4*)wfb, coefs + 128,
                               b3, x, out);
}

// Round 17
// 117.766 us; speedup vs baseline: 1.0532x; 1.0532x over previous
//
#include <hip/hip_runtime.h>
#include <hip/hip_bf16.h>

#define N_NODES 50000
#define KNN     16
#define NEDGE   (N_NODES*KNN)     // 800000
#define NTILE2  (NEDGE/128)       // 6250 tiles of 128 edges (8 nodes)
#define NWT     (N_NODES/16)      // 3125 wave-tiles for kUV
#define NBG     2048              // grid kS1/kS2/kS3
#define SLOPE   0.01f
#define EPS     1e-5f

typedef __attribute__((ext_vector_type(8))) short bf16x8;
typedef __attribute__((ext_vector_type(4))) float f32x4;

__device__ __forceinline__ float bfbits(unsigned u){ union{unsigned u;float f;}v; v.u=u; return v.f; }
__device__ __forceinline__ unsigned fbits(float f){ union{float f;unsigned u;}v; v.f=f; return v.u; }
__device__ __forceinline__ unsigned pk2(float a, float b){
  const unsigned ua = fbits(a) + 0x8000u;
  const unsigned ub = fbits(b) + 0x8000u;
  return __builtin_amdgcn_perm(ub, ua, 0x07060302u);
}
__device__ __forceinline__ unsigned short f2bfr(float f){
  return (unsigned short)((fbits(f) + 0x8000u) >> 16);
}
__device__ __forceinline__ bf16x8 asfrag(uint4 u){ union{uint4 v; bf16x8 b;}q; q.v=u; return q.b; }
__device__ __forceinline__ f32x4 MFMA(bf16x8 a, bf16x8 b, f32x4 c){
  return __builtin_amdgcn_mfma_f32_16x16x32_bf16(a, b, c, 0, 0, 0);
}
__device__ __forceinline__ float lrelu(float v){ return v>=0.f ? v : SLOPE*v; }

__device__ __forceinline__ void unp8(bf16x8 v, float* o){
  union{bf16x8 b; unsigned u[4];}q; q.b=v;
#pragma unroll
  for (int w=0;w<4;++w){
    o[2*w]   = bfbits(q.u[w]<<16);
    o[2*w+1] = bfbits(q.u[w]&0xffff0000u);
  }
}
__device__ __forceinline__ bf16x8 pack8r(const float* f){
  union{unsigned u[4]; bf16x8 b;}q;
#pragma unroll
  for (int i=0;i<4;++i) q.u[i] = pk2(f[2*i], f[2*i+1]);
  return q.b;
}
__device__ __forceinline__ bf16x8 pack8v(float4 a, float4 b){
  union{unsigned u[4]; bf16x8 v;}q;
  q.u[0]=pk2(a.x,a.y); q.u[1]=pk2(a.z,a.w);
  q.u[2]=pk2(b.x,b.y); q.u[3]=pk2(b.z,b.w);
  return q.v;
}

// ---- kInit: pack W frags. W1 folded: frags 0..7 = A-B, 8..15 = B -----------
__global__ __launch_bounds__(256) void kInit(const float* __restrict__ W1,
    const float* __restrict__ W2, const float* __restrict__ W3,
    unsigned short* __restrict__ wf)
{
  const int idx = blockIdx.x*256 + threadIdx.x;   // 2048 entries
  const float* W; int fi; bool fold = false;
  if (idx < 1024)      { W = W1; fi = idx >> 6; fold = (idx < 512); }
  else if (idx < 1536) { W = W2; fi = (idx-1024) >> 6; }
  else                 { W = W3; fi = (idx-1536) >> 6; }
  const int l  = idx & 63;
  const int ks = fi >> 2, nf = fi & 3;
  const int k0 = ks*32 + ((l>>4)<<3);
  const int col = nf*16 + (l&15);
  unsigned short* o = wf + (size_t)idx*8;
#pragma unroll
  for (int e=0;e<8;++e){
    float v = W[(size_t)(k0+e)*64 + col];
    if (fold) v -= W[(size_t)(k0+e+64)*64 + col];
    o[e] = f2bfr(v);
  }
}

// ---- kUV: per-node U = x(A-B), V = xB (bf16) -------------------------------
__global__ __launch_bounds__(256) void kUV(const float* __restrict__ x,
    const uint4* __restrict__ wf, unsigned short* __restrict__ Ub,
    unsigned short* __restrict__ Vb)
{
  const int t = threadIdx.x, w = t>>6, l = t&63, lr = l&15, lg = l>>4;
  const int wt = blockIdx.x*4 + w;
  if (wt >= NWT) return;
  bf16x8 wfr[16];
#pragma unroll
  for (int f=0;f<16;++f) wfr[f] = asfrag(wf[f*64 + l]);
  const int n0 = wt*16;
  const float* xr = x + (size_t)(n0+lr)*64 + lg*8;
  const bf16x8 a0 = pack8v(((const float4*)xr)[0],      ((const float4*)xr)[1]);
  const bf16x8 a1 = pack8v(((const float4*)(xr+32))[0], ((const float4*)(xr+32))[1]);

  f32x4 aU[4], aV[4];
#pragma unroll
  for (int nf=0;nf<4;++nf){
    aU[nf] = (f32x4){0,0,0,0};
    aU[nf] = MFMA(a0, wfr[nf],    aU[nf]);
    aU[nf] = MFMA(a1, wfr[4+nf],  aU[nf]);
    aV[nf] = (f32x4){0,0,0,0};
    aV[nf] = MFMA(a0, wfr[8+nf],  aV[nf]);
    aV[nf] = MFMA(a1, wfr[12+nf], aV[nf]);
  }
#pragma unroll
  for (int nf=0;nf<4;++nf)
#pragma unroll
    for (int r=0;r<4;++r){
      const size_t o = (size_t)(n0 + 4*lg + r)*64 + 16*nf + lr;
      Ub[o] = f2bfr(aU[nf][r]);
      Vb[o] = f2bfr(aV[nf][r]);
    }
}

#define LOADUV(U0,U1,V0,V1, nodeId, srcId)                               \
  {                                                                      \
    const unsigned short* Ur = Ub + (size_t)(nodeId)*64 + lg*8;          \
    const unsigned short* Vr = Vb + (size_t)(srcId)*64  + lg*8;          \
    U0 = *(const bf16x8*)(Ur); U1 = *(const bf16x8*)(Ur + 32);           \
    V0 = *(const bf16x8*)(Vr); V1 = *(const bf16x8*)(Vr + 32);           \
  }

#define H1COMP(h0f, h1f, U0,U1,V0,V1)                                   \
  bf16x8 h0f, h1f;                                                      \
  {                                                                     \
    float fu[8], fv[8], h[8];                                           \
    unp8(U0,fu); unp8(V0,fv);                                           \
    _Pragma("unroll")                                                   \
    for (int e=0;e<8;++e) h[e] = lrelu(fu[e]+fv[e]);                    \
    h0f = pack8r(h);                                                    \
    unp8(U1,fu); unp8(V1,fv);                                           \
    _Pragma("unroll")                                                   \
    for (int e=0;e<8;++e) h[e] = lrelu(fu[e]+fv[e]);                    \
    h1f = pack8r(h);                                                    \
  }

// ---- kS1: 2-node ILP; stats of z1 = U[dst] + V[src] (no MFMA) --------------
__global__ __launch_bounds__(256,4) void kS1(const unsigned short* __restrict__ Ub,
    const unsigned short* __restrict__ Vb, const int* __restrict__ ei,
    float* __restrict__ part)
{
  __shared__ float red[4][128];
  const int t = threadIdx.x, w = t>>6, l = t&63, lr = l&15, lg = l>>4;
  const int G = gridDim.x;

  float s[16], q[16];
#pragma unroll
  for (int k=0;k<16;++k){ s[k]=0.f; q[k]=0.f; }

  int tile = blockIdx.x;
  int srcA = ei[tile*128 + (2*w)*16 + lr];
  int srcB = ei[tile*128 + (2*w+1)*16 + lr];
  for (; tile < NTILE2; tile += G){
    const int nA = tile*8 + 2*w, nB = nA + 1;
    bf16x8 uA0,uA1,vA0,vA1, uB0,uB1,vB0,vB1;
    LOADUV(uA0,uA1,vA0,vA1, nA, srcA)
    LOADUV(uB0,uB1,vB0,vB1, nB, srcB)
    const int nt = tile + G;
    if (nt < NTILE2){
      srcA = ei[nt*128 + (2*w)*16 + lr];
      srcB = ei[nt*128 + (2*w+1)*16 + lr];
    }

    float fu[8], fv[8];
    unp8(uA0,fu); unp8(vA0,fv);
#pragma unroll
    for (int e=0;e<8;++e){ const float z = fu[e]+fv[e]; s[e]+=z; q[e]=fmaf(z,z,q[e]); }
    unp8(uA1,fu); unp8(vA1,fv);
#pragma unroll
    for (int e=0;e<8;++e){ const float z = fu[e]+fv[e]; s[8+e]+=z; q[8+e]=fmaf(z,z,q[8+e]); }
    unp8(uB0,fu); unp8(vB0,fv);
#pragma unroll
    for (int e=0;e<8;++e){ const float z = fu[e]+fv[e]; s[e]+=z; q[e]=fmaf(z,z,q[e]); }
    unp8(uB1,fu); unp8(vB1,fv);
#pragma unroll
    for (int e=0;e<8;++e){ const float z = fu[e]+fv[e]; s[8+e]+=z; q[8+e]=fmaf(z,z,q[8+e]); }
  }

#pragma unroll
  for (int k=0;k<16;++k){
    float a=s[k]; a+=__shfl_xor(a,1,64); a+=__shfl_xor(a,2,64);
    a+=__shfl_xor(a,4,64); a+=__shfl_xor(a,8,64); s[k]=a;
    float b=q[k]; b+=__shfl_xor(b,1,64); b+=__shfl_xor(b,2,64);
    b+=__shfl_xor(b,4,64); b+=__shfl_xor(b,8,64); q[k]=b;
  }
  if (lr == 0){
#pragma unroll
    for (int e=0;e<8;++e){
      red[w][8*lg+e]    = s[e];
      red[w][32+8*lg+e] = s[8+e];
      red[w][64+8*lg+e] = q[e];
      red[w][96+8*lg+e] = q[8+e];
    }
  }
  __syncthreads();
  if (t < 128)
    part[(size_t)t*NBG + blockIdx.x] = red[0][t]+red[1][t]+red[2][t]+red[3][t];
}

// ---- kFin: 64 blocks, block c reduces sum/sq rows over nb entries ----------
__global__ __launch_bounds__(256) void kFin(const float* __restrict__ part,
    const float* __restrict__ g, const float* __restrict__ be,
    float* __restrict__ coefs, int nb)
{
  __shared__ float rs[256], rq[256];
  const int c = blockIdx.x, t = threadIdx.x;
  const float* ps = part + (size_t)c*nb;
  const float* pq = part + (size_t)(64+c)*nb;
  float s = 0.f, q = 0.f;
  for (int i=t; i<nb; i+=256){ s += ps[i]; q += pq[i]; }
  rs[t]=s; rq[t]=q;
  __syncthreads();
#pragma unroll
  for (int off=128; off>0; off>>=1){
    if (t < off){ rs[t]+=rs[t+off]; rq[t]+=rq[t+off]; }
    __syncthreads();
  }
  if (t==0){
    const float inv  = 1.0f/(float)NEDGE;
    const float mean = rs[0]*inv;
    const float var  = rq[0]*inv - mean*mean;
    const float a    = g[c]*rsqrtf(var + EPS);
    coefs[c]      = a;
    coefs[64 + c] = be[c] - mean*a;
  }
}

// ---- kScale: U' = a*U + c ; V' = a*V (in place, fold BN1) ------------------
__global__ __launch_bounds__(256) void kScale(unsigned short* __restrict__ Ub,
    unsigned short* __restrict__ Vb, const float* __restrict__ coefs)
{
  const int j = blockIdx.x*256 + threadIdx.x;
  if (j >= N_NODES*8) return;
  const int c0 = (j & 7)*8;
  float a[8], c[8], f[8];
#pragma unroll
  for (int e=0;e<8;++e){ a[e]=coefs[c0+e]; c[e]=coefs[64+c0+e]; }
  bf16x8 u = ((const bf16x8*)Ub)[j];
  unp8(u,f);
#pragma unroll
  for (int e=0;e<8;++e) f[e] = fmaf(a[e], f[e], c[e]);
  ((bf16x8*)Ub)[j] = pack8r(f);
  bf16x8 v = ((const bf16x8*)Vb)[j];
  unp8(v,f);
#pragma unroll
  for (int e=0;e<8;++e) f[e] *= a[e];
  ((bf16x8*)Vb)[j] = pack8r(f);
}

// ---- kS2: 2-node ILP; h1 = lrelu(U'+V'); z2 = h1@W2; stats2 ----------------
__global__ __launch_bounds__(256,4) void kS2(const unsigned short* __restrict__ Ub,
    const unsigned short* __restrict__ Vb, const int* __restrict__ ei,
    const uint4* __restrict__ wfg, float* __restrict__ part)
{
  __shared__ uint4 wlds[512];          // wf2 table, 8 KB
  __shared__ float red[4][128];
  const int t = threadIdx.x, w = t>>6, l = t&63, lr = l&15, lg = l>>4;
  const int G = gridDim.x;
  const f32x4 Z4 = (f32x4){0.f,0.f,0.f,0.f};

  for (int i=t; i<512; i+=256) wlds[i] = wfg[1024+i];
  __syncthreads();

  float sumP[4] = {0,0,0,0}, sqP[4] = {0,0,0,0};

  int tile = blockIdx.x;
  int srcA = ei[tile*128 + (2*w)*16 + lr];
  int srcB = ei[tile*128 + (2*w+1)*16 + lr];
  for (; tile < NTILE2; tile += G){
    const int nA = tile*8 + 2*w, nB = nA + 1;
    bf16x8 uA0,uA1,vA0,vA1, uB0,uB1,vB0,vB1;
    LOADUV(uA0,uA1,vA0,vA1, nA, srcA)
    LOADUV(uB0,uB1,vB0,vB1, nB, srcB)
    const int nt = tile + G;
    if (nt < NTILE2){
      srcA = ei[nt*128 + (2*w)*16 + lr];
      srcB = ei[nt*128 + (2*w+1)*16 + lr];
    }

    H1COMP(hA0, hA1, uA0,uA1,vA0,vA1)
    H1COMP(hB0, hB1, uB0,uB1,vB0,vB1)

    f32x4 aA[4], aB[4];
#pragma unroll
    for (int nf=0;nf<4;++nf){
      const bf16x8 b0 = asfrag(wlds[nf*64 + l]);
      const bf16x8 b1 = asfrag(wlds[(4+nf)*64 + l]);
      aA[nf] = MFMA(hA0, b0, Z4);  aA[nf] = MFMA(hA1, b1, aA[nf]);
      aB[nf] = MFMA(hB0, b0, Z4);  aB[nf] = MFMA(hB1, b1, aB[nf]);
    }
#pragma unroll
    for (int nf=0;nf<4;++nf)
#pragma unroll
      for (int r=0;r<4;++r){
        const float v0 = aA[nf][r], v1 = aB[nf][r];
        sumP[nf] += v0 + v1;
        sqP[nf] = fmaf(v0,v0,sqP[nf]);
        sqP[nf] = fmaf(v1,v1,sqP[nf]);
      }
  }

#pragma unroll
  for (int nf=0;nf<4;++nf){
    float s = sumP[nf], q = sqP[nf];
    s += __shfl_xor(s,16,64); s += __shfl_xor(s,32,64);
    q += __shfl_xor(q,16,64); q += __shfl_xor(q,32,64);
    if (l < 16){ red[w][nf*16+l] = s; red[w][64+nf*16+l] = q; }
  }
  __syncthreads();
  if (t < 128)
    part[(size_t)t*NBG + blockIdx.x] = red[0][t]+red[1][t]+red[2][t]+red[3][t];
}

// ---- kS3: 2-node ILP; one per-wave transpose buffer (LDS 25KB -> 6 blk/CU) -
__global__ __launch_bounds__(256,4) void kS3(const unsigned short* __restrict__ Ub,
    const unsigned short* __restrict__ Vb, const int* __restrict__ ei,
    const uint4* __restrict__ wfg, const float* __restrict__ coefs2,
    const float* __restrict__ b3, const float* __restrict__ x,
    float* __restrict__ out)
{
  __shared__ uint4 wlds[1024];                              // wf2|wf3, 16 KB
  __shared__ __align__(16) unsigned short buf[4][16][72];   // per-wave, 9.2 KB
  const int t = threadIdx.x, w = t>>6, l = t&63, lr = l&15, lg = l>>4;
  const int G = gridDim.x;
  const f32x4 Z4 = (f32x4){0.f,0.f,0.f,0.f};

  for (int i=t; i<1024; i+=256) wlds[i] = wfg[1024+i];
  __syncthreads();

  float a2v[4], c2v[4], bb[4];
#pragma unroll
  for (int nf=0;nf<4;++nf){
    a2v[nf]=coefs2[nf*16+lr]; c2v[nf]=coefs2[64+nf*16+lr];
    bb[nf] = b3[nf*16+lr];
  }

  int tile = blockIdx.x;
  int srcA = ei[tile*128 + (2*w)*16 + lr];
  int srcB = ei[tile*128 + (2*w+1)*16 + lr];
  for (; tile < NTILE2; tile += G){
    const int nA = tile*8 + 2*w, nB = nA + 1;
    bf16x8 uA0,uA1,vA0,vA1, uB0,uB1,vB0,vB1;
    LOADUV(uA0,uA1,vA0,vA1, nA, srcA)
    LOADUV(uB0,uB1,vB0,vB1, nB, srcB)
    const int nt = tile + G;
    if (nt < NTILE2){
      srcA = ei[nt*128 + (2*w)*16 + lr];
      srcB = ei[nt*128 + (2*w+1)*16 + lr];
    }

    H1COMP(hA0, hA1, uA0,uA1,vA0,vA1)
    H1COMP(hB0, hB1, uB0,uB1,vB0,vB1)

    // GEMM2 (unswapped): D = z2[edge 4lg+r][ch 16nf+lr]
    f32x4 aA[4], aB[4];
#pragma unroll
    for (int nf=0;nf<4;++nf){
      const bf16x8 b0 = asfrag(wlds[nf*64 + l]);
      const bf16x8 b1 = asfrag(wlds[(4+nf)*64 + l]);
      aA[nf] = MFMA(hA0, b0, Z4);  aA[nf] = MFMA(hA1, b1, aA[nf]);
      aB[nf] = MFMA(hB0, b0, Z4);  aB[nf] = MFMA(hB1, b1, aB[nf]);
    }
    // stream A: BN2+lrelu -> buf -> read A-frags (same-wave DS pipe is in-order)
#pragma unroll
    for (int nf=0;nf<4;++nf)
#pragma unroll
      for (int r=0;r<4;++r)
        buf[w][4*lg+r][16*nf+lr] = f2bfr(lrelu(fmaf(a2v[nf], aA[nf][r], c2v[nf])));
    const bf16x8 gA0 = *(const bf16x8*)&buf[w][lr][8*lg];
    const bf16x8 gA1 = *(const bf16x8*)&buf[w][lr][32+8*lg];
    // stream B: reuse the same buffer (writes ordered after reads above)
#pragma unroll
    for (int nf=0;nf<4;++nf)
#pragma unroll
      for (int r=0;r<4;++r)
        buf[w][4*lg+r][16*nf+lr] = f2bfr(lrelu(fmaf(a2v[nf], aB[nf][r], c2v[nf])));
    const bf16x8 gB0 = *(const bf16x8*)&buf[w][lr][8*lg];
    const bf16x8 gB1 = *(const bf16x8*)&buf[w][lr][32+8*lg];

    f32x4 cA[4], cB[4];
#pragma unroll
    for (int nf=0;nf<4;++nf){
      const bf16x8 b0 = asfrag(wlds[512 + nf*64 + l]);
      const bf16x8 b1 = asfrag(wlds[512 + (4+nf)*64 + l]);
      cA[nf] = MFMA(gA0, b0, Z4);  cA[nf] = MFMA(gA1, b1, cA[nf]);
      cB[nf] = MFMA(gB0, b0, Z4);  cB[nf] = MFMA(gB1, b1, cB[nf]);
    }

    // segmax over each node's 16 edges; bias after max; residual
#pragma unroll
    for (int nf=0;nf<4;++nf){
      float mA = fmaxf(fmaxf(cA[nf][0],cA[nf][1]), fmaxf(cA[nf][2],cA[nf][3]));
      mA = fmaxf(mA, __shfl_xor(mA,16,64));
      mA = fmaxf(mA, __shfl_xor(mA,32,64));
      float mB = fmaxf(fmaxf(cB[nf][0],cB[nf][1]), fmaxf(cB[nf][2],cB[nf][3]));
      mB = fmaxf(mB, __shfl_xor(mB,16,64));
      mB = fmaxf(mB, __shfl_xor(mB,32,64));
      if (l < 16){
        const float xA = x[(size_t)nA*64 + nf*16 + l];
        out[(size_t)nA*64 + nf*16 + l] = lrelu(mA + bb[nf] + xA);
        const float xB = x[(size_t)nB*64 + nf*16 + l];
        out[(size_t)nB*64 + nf*16 + l] = lrelu(mB + bb[nf] + xB);
      }
    }
  }
}

extern "C" void kernel_launch(void* const* d_in, const int* in_sizes, int n_in,
                              void* d_out, int out_size, void* d_ws, size_t ws_size,
                              hipStream_t stream) {
  const float* x   = (const float*)d_in[0];
  const int*   ei  = (const int*)d_in[1];
  const float* W1  = (const float*)d_in[2];
  const float* g1  = (const float*)d_in[4];
  const float* be1 = (const float*)d_in[5];
  const float* W2  = (const float*)d_in[6];
  const float* g2  = (const float*)d_in[8];
  const float* be2 = (const float*)d_in[9];
  const float* W3  = (const float*)d_in[10];
  const float* b3  = (const float*)d_in[11];
  float* out = (float*)d_out;

  // ws: coefs 1KB | part1 1MB | part2 1MB | wfb 32KB | U 6.4MB | V 6.4MB
  float*          coefs = (float*)d_ws;
  float*          part1 = (float*)((char*)d_ws + 1024);
  float*          part2 = part1 + (size_t)NBG*128;
  unsigned short* wfb   = (unsigned short*)((char*)part2 + (size_t)NBG*128*4);
  unsigned short* Ub    = (unsigned short*)((char*)wfb + 32768);
  unsigned short* Vb    = Ub + (size_t)N_NODES*64;

  kInit<<<8, 256, 0, stream>>>(W1, W2, W3, wfb);
  kUV<<<(NWT+3)/4, 256, 0, stream>>>(x, (const uint4*)wfb, Ub, Vb);
  kS1<<<NBG, 256, 0, stream>>>(Ub, Vb, ei, part1);
  kFin<<<64, 256, 0, stream>>>(part1, g1, be1, coefs, NBG);
  kScale<<<(N_NODES*8 + 255)/256, 256, 0, stream>>>(Ub, Vb, coefs);
  kS2<<<NBG, 256, 0, stream>>>(Ub, Vb, ei, (const uint4*)wfb, part2);
  kFin<<<64, 256, 0, stream>>>(part2, g2, be2, coefs + 128, NBG);
  kS3<<<NBG, 256, 0, stream>>>(Ub, Vb, ei, (const uint4*)wfb, coefs + 128,
                               b3, x, out);
}

// Round 18
// 108.395 us; speedup vs baseline: 1.1442x; 1.0864x over previous
//
#include <hip/hip_runtime.h>
#include <hip/hip_fp16.h>

#define N_NODES 50000
#define KNN     16
#define NEDGE   (N_NODES*KNN)     // 800000
#define NTILE2  (NEDGE/128)       // 6250 tiles of 128 edges (8 nodes)
#define NWT     (N_NODES/16)      // 3125 wave-tiles for kUV
#define NB2     1024              // grid kS1/kS2/kS3
#define SLOPE   0.01f
#define EPS     1e-5f

typedef __attribute__((ext_vector_type(8))) _Float16 f16x8;
typedef __attribute__((ext_vector_type(4))) float f32x4;

__device__ __forceinline__ unsigned short f2h(float f){
  union{_Float16 h; unsigned short u;} v; v.h = (_Float16)f; return v.u;
}
__device__ __forceinline__ unsigned short h2u(_Float16 h){
  union{_Float16 h; unsigned short u;} v; v.h = h; return v.u;
}
__device__ __forceinline__ f32x4 MFMA(f16x8 a, f16x8 b, f32x4 c){
  return __builtin_amdgcn_mfma_f32_16x16x32_f16(a, b, c, 0, 0, 0);
}
__device__ __forceinline__ float lrelu(float v){ return v>=0.f ? v : SLOPE*v; }

// ---- kInit: pack W frags (fp16). W1 folded: frags 0..7 = A-B, 8..15 = B ----
__global__ __launch_bounds__(256) void kInit(const float* __restrict__ W1,
    const float* __restrict__ W2, const float* __restrict__ W3,
    unsigned short* __restrict__ wf)
{
  const int idx = blockIdx.x*256 + threadIdx.x;   // 2048 entries
  const float* W; int fi; bool fold = false;
  if (idx < 1024)      { W = W1; fi = idx >> 6; fold = (idx < 512); }
  else if (idx < 1536) { W = W2; fi = (idx-1024) >> 6; }
  else                 { W = W3; fi = (idx-1536) >> 6; }
  const int l  = idx & 63;
  const int ks = fi >> 2, nf = fi & 3;
  const int k0 = ks*32 + ((l>>4)<<3);
  const int col = nf*16 + (l&15);
  unsigned short* o = wf + (size_t)idx*8;
#pragma unroll
  for (int e=0;e<8;++e){
    float v = W[(size_t)(k0+e)*64 + col];
    if (fold) v -= W[(size_t)(k0+e+64)*64 + col];
    o[e] = f2h(v);
  }
}

// ---- kUV: per-node U = x(A-B), V = xB (fp16) -------------------------------
__global__ __launch_bounds__(256) void kUV(const float* __restrict__ x,
    const uint4* __restrict__ wf, unsigned short* __restrict__ Ub,
    unsigned short* __restrict__ Vb)
{
  const int t = threadIdx.x, w = t>>6, l = t&63, lr = l&15, lg = l>>4;
  const int wt = blockIdx.x*4 + w;
  if (wt >= NWT) return;
  f16x8 wfr[16];
#pragma unroll
  for (int f=0;f<16;++f){ union{uint4 v; f16x8 h;}q; q.v = wf[f*64 + l]; wfr[f]=q.h; }
  const int n0 = wt*16;
  const float* xr = x + (size_t)(n0+lr)*64 + lg*8;
  f16x8 a0, a1;
#pragma unroll
  for (int e=0;e<8;++e){ a0[e] = (_Float16)xr[e]; a1[e] = (_Float16)xr[32+e]; }

  f32x4 aU[4], aV[4];
#pragma unroll
  for (int nf=0;nf<4;++nf){
    aU[nf] = (f32x4){0,0,0,0};
    aU[nf] = MFMA(a0, wfr[nf],    aU[nf]);
    aU[nf] = MFMA(a1, wfr[4+nf],  aU[nf]);
    aV[nf] = (f32x4){0,0,0,0};
    aV[nf] = MFMA(a0, wfr[8+nf],  aV[nf]);
    aV[nf] = MFMA(a1, wfr[12+nf], aV[nf]);
  }
#pragma unroll
  for (int nf=0;nf<4;++nf)
#pragma unroll
    for (int r=0;r<4;++r){
      const size_t o = (size_t)(n0 + 4*lg + r)*64 + 16*nf + lr;
      Ub[o] = f2h(aU[nf][r]);
      Vb[o] = f2h(aV[nf][r]);
    }
}

#define LOADUV(U0,U1,V0,V1, nodeId, srcId)                               \
  {                                                                      \
    const unsigned short* Ur = Ub + (size_t)(nodeId)*64 + lg*8;          \
    const unsigned short* Vr = Vb + (size_t)(srcId)*64  + lg*8;          \
    U0 = *(const f16x8*)(Ur); U1 = *(const f16x8*)(Ur + 32);             \
    V0 = *(const f16x8*)(Vr); V1 = *(const f16x8*)(Vr + 32);             \
  }

// h1 = lrelu(U'+V') fully in packed fp16: 12 v_pk ops per 8 elems
#define H1COMP(h0f, h1f, U0,U1,V0,V1)                                   \
  f16x8 h0f, h1f;                                                       \
  {                                                                     \
    const f16x8 s0 = U0 + V0, s1 = U1 + V1;                             \
    h0f = __builtin_elementwise_max(s0, s0 * (_Float16)0.01f);          \
    h1f = __builtin_elementwise_max(s1, s1 * (_Float16)0.01f);          \
  }

// ---- kS1: 2-node ILP; stats of z1 = U[dst] + V[src] (no MFMA) --------------
__global__ __launch_bounds__(256,4) void kS1(const unsigned short* __restrict__ Ub,
    const unsigned short* __restrict__ Vb, const int* __restrict__ ei,
    float* __restrict__ part)
{
  __shared__ float red[4][128];
  const int t = threadIdx.x, w = t>>6, l = t&63, lr = l&15, lg = l>>4;
  const int G = gridDim.x;

  float s[16], q[16];
#pragma unroll
  for (int k=0;k<16;++k){ s[k]=0.f; q[k]=0.f; }

#define ACCST(U0,U1,V0,V1)                                              \
  {                                                                     \
    const f16x8 z0 = U0 + V0, z1 = U1 + V1;                             \
    _Pragma("unroll")                                                   \
    for (int e=0;e<8;++e){ const float zf=(float)z0[e]; s[e]+=zf; q[e]=fmaf(zf,zf,q[e]); } \
    _Pragma("unroll")                                                   \
    for (int e=0;e<8;++e){ const float zf=(float)z1[e]; s[8+e]+=zf; q[8+e]=fmaf(zf,zf,q[8+e]); } \
  }

  int tile = blockIdx.x;
  int srcA = ei[tile*128 + (2*w)*16 + lr];
  int srcB = ei[tile*128 + (2*w+1)*16 + lr];
  for (; tile < NTILE2; tile += G){
    const int nA = tile*8 + 2*w, nB = nA + 1;
    f16x8 uA0,uA1,vA0,vA1, uB0,uB1,vB0,vB1;
    LOADUV(uA0,uA1,vA0,vA1, nA, srcA)
    LOADUV(uB0,uB1,vB0,vB1, nB, srcB)
    const int nt = tile + G;
    if (nt < NTILE2){
      srcA = ei[nt*128 + (2*w)*16 + lr];
      srcB = ei[nt*128 + (2*w+1)*16 + lr];
    }
    ACCST(uA0,uA1,vA0,vA1)
    ACCST(uB0,uB1,vB0,vB1)
  }

#pragma unroll
  for (int k=0;k<16;++k){
    float a=s[k]; a+=__shfl_xor(a,1,64); a+=__shfl_xor(a,2,64);
    a+=__shfl_xor(a,4,64); a+=__shfl_xor(a,8,64); s[k]=a;
    float b=q[k]; b+=__shfl_xor(b,1,64); b+=__shfl_xor(b,2,64);
    b+=__shfl_xor(b,4,64); b+=__shfl_xor(b,8,64); q[k]=b;
  }
  if (lr == 0){
#pragma unroll
    for (int e=0;e<8;++e){
      red[w][8*lg+e]    = s[e];
      red[w][32+8*lg+e] = s[8+e];
      red[w][64+8*lg+e] = q[e];
      red[w][96+8*lg+e] = q[8+e];
    }
  }
  __syncthreads();
  if (t < 128)
    part[(size_t)t*NB2 + blockIdx.x] = red[0][t]+red[1][t]+red[2][t]+red[3][t];
}

// ---- kFin: 64 blocks, block c reduces sum/sq rows over nb entries ----------
__global__ __launch_bounds__(256) void kFin(const float* __restrict__ part,
    const float* __restrict__ g, const float* __restrict__ be,
    float* __restrict__ coefs, int nb)
{
  __shared__ float rs[256], rq[256];
  const int c = blockIdx.x, t = threadIdx.x;
  const float* ps = part + (size_t)c*nb;
  const float* pq = part + (size_t)(64+c)*nb;
  float s = 0.f, q = 0.f;
  for (int i=t; i<nb; i+=256){ s += ps[i]; q += pq[i]; }
  rs[t]=s; rq[t]=q;
  __syncthreads();
#pragma unroll
  for (int off=128; off>0; off>>=1){
    if (t < off){ rs[t]+=rs[t+off]; rq[t]+=rq[t+off]; }
    __syncthreads();
  }
  if (t==0){
    const float inv  = 1.0f/(float)NEDGE;
    const float mean = rs[0]*inv;
    const float var  = rq[0]*inv - mean*mean;
    const float a    = g[c]*rsqrtf(var + EPS);
    coefs[c]      = a;
    coefs[64 + c] = be[c] - mean*a;
  }
}

// ---- kScale: U' = a*U + c ; V' = a*V (in place, fold BN1) ------------------
__global__ __launch_bounds__(256) void kScale(unsigned short* __restrict__ Ub,
    unsigned short* __restrict__ Vb, const float* __restrict__ coefs)
{
  const int j = blockIdx.x*256 + threadIdx.x;
  if (j >= N_NODES*8) return;
  const int c0 = (j & 7)*8;
  float a[8], c[8];
#pragma unroll
  for (int e=0;e<8;++e){ a[e]=coefs[c0+e]; c[e]=coefs[64+c0+e]; }
  f16x8 u = ((const f16x8*)Ub)[j];
#pragma unroll
  for (int e=0;e<8;++e) u[e] = (_Float16)fmaf(a[e], (float)u[e], c[e]);
  ((f16x8*)Ub)[j] = u;
  f16x8 v = ((const f16x8*)Vb)[j];
#pragma unroll
  for (int e=0;e<8;++e) v[e] = (_Float16)(a[e] * (float)v[e]);
  ((f16x8*)Vb)[j] = v;
}

// ---- kS2: 2-node ILP; h1 = lrelu(U'+V'); z2 = h1@W2; stats2 ----------------
__global__ __launch_bounds__(256,4) void kS2(const unsigned short* __restrict__ Ub,
    const unsigned short* __restrict__ Vb, const int* __restrict__ ei,
    const uint4* __restrict__ wfg, float* __restrict__ part)
{
  __shared__ uint4 wlds[512];          // wf2 table, 8 KB
  __shared__ float red[4][128];
  const int t = threadIdx.x, w = t>>6, l = t&63, lr = l&15, lg = l>>4;
  const int G = gridDim.x;
  const f32x4 Z4 = (f32x4){0.f,0.f,0.f,0.f};

  for (int i=t; i<512; i+=256) wlds[i] = wfg[1024+i];
  __syncthreads();

  float sumP[4] = {0,0,0,0}, sqP[4] = {0,0,0,0};

  int tile = blockIdx.x;
  int srcA = ei[tile*128 + (2*w)*16 + lr];
  int srcB = ei[tile*128 + (2*w+1)*16 + lr];
  for (; tile < NTILE2; tile += G){
    const int nA = tile*8 + 2*w, nB = nA + 1;
    f16x8 uA0,uA1,vA0,vA1, uB0,uB1,vB0,vB1;
    LOADUV(uA0,uA1,vA0,vA1, nA, srcA)
    LOADUV(uB0,uB1,vB0,vB1, nB, srcB)
    const int nt = tile + G;
    if (nt < NTILE2){
      srcA = ei[nt*128 + (2*w)*16 + lr];
      srcB = ei[nt*128 + (2*w+1)*16 + lr];
    }

    H1COMP(hA0, hA1, uA0,uA1,vA0,vA1)
    H1COMP(hB0, hB1, uB0,uB1,vB0,vB1)

    f32x4 aA[4], aB[4];
#pragma unroll
    for (int nf=0;nf<4;++nf){
      union{uint4 v; f16x8 h;}q0, q1;
      q0.v = wlds[nf*64 + l];  q1.v = wlds[(4+nf)*64 + l];
      aA[nf] = MFMA(hA0, q0.h, Z4);  aA[nf] = MFMA(hA1, q1.h, aA[nf]);
      aB[nf] = MFMA(hB0, q0.h, Z4);  aB[nf] = MFMA(hB1, q1.h, aB[nf]);
    }
#pragma unroll
    for (int nf=0;nf<4;++nf)
#pragma unroll
      for (int r=0;r<4;++r){
        const float v0 = aA[nf][r], v1 = aB[nf][r];
        sumP[nf] += v0 + v1;
        sqP[nf] = fmaf(v0,v0,sqP[nf]);
        sqP[nf] = fmaf(v1,v1,sqP[nf]);
      }
  }

#pragma unroll
  for (int nf=0;nf<4;++nf){
    float s = sumP[nf], q = sqP[nf];
    s += __shfl_xor(s,16,64); s += __shfl_xor(s,32,64);
    q += __shfl_xor(q,16,64); q += __shfl_xor(q,32,64);
    if (l < 16){ red[w][nf*16+l] = s; red[w][64+nf*16+l] = q; }
  }
  __syncthreads();
  if (t < 128)
    part[(size_t)t*NB2 + blockIdx.x] = red[0][t]+red[1][t]+red[2][t]+red[3][t];
}

// ---- kS3: 2-node ILP; h1 -> z2 -> BN2+lrelu -> z3 -> segmax -> out ---------
__global__ __launch_bounds__(256,4) void kS3(const unsigned short* __restrict__ Ub,
    const unsigned short* __restrict__ Vb, const int* __restrict__ ei,
    const uint4* __restrict__ wfg, const float* __restrict__ coefs2,
    const float* __restrict__ b3, const float* __restrict__ x,
    float* __restrict__ out)
{
  __shared__ uint4 wlds[1024];                              // wf2|wf3, 16 KB
  __shared__ __align__(16) unsigned short buf[8][16][72];   // per-stream, 18 KB
  const int t = threadIdx.x, w = t>>6, l = t&63, lr = l&15, lg = l>>4;
  const int G = gridDim.x;
  const f32x4 Z4 = (f32x4){0.f,0.f,0.f,0.f};

  for (int i=t; i<1024; i+=256) wlds[i] = wfg[1024+i];
  __syncthreads();

  float a2v[4], c2v[4], bb[4];
#pragma unroll
  for (int nf=0;nf<4;++nf){
    a2v[nf]=coefs2[nf*16+lr]; c2v[nf]=coefs2[64+nf*16+lr];
    bb[nf] = b3[nf*16+lr];
  }

  int tile = blockIdx.x;
  int srcA = ei[tile*128 + (2*w)*16 + lr];
  int srcB = ei[tile*128 + (2*w+1)*16 + lr];
  for (; tile < NTILE2; tile += G){
    const int nA = tile*8 + 2*w, nB = nA + 1;
    f16x8 uA0,uA1,vA0,vA1, uB0,uB1,vB0,vB1;
    LOADUV(uA0,uA1,vA0,vA1, nA, srcA)
    LOADUV(uB0,uB1,vB0,vB1, nB, srcB)
    const int nt = tile + G;
    if (nt < NTILE2){
      srcA = ei[nt*128 + (2*w)*16 + lr];
      srcB = ei[nt*128 + (2*w+1)*16 + lr];
    }

    H1COMP(hA0, hA1, uA0,uA1,vA0,vA1)
    H1COMP(hB0, hB1, uB0,uB1,vB0,vB1)

    // GEMM2 (unswapped): D = z2[edge 4lg+r][ch 16nf+lr]; B shared across streams
    f32x4 aA[4], aB[4];
#pragma unroll
    for (int nf=0;nf<4;++nf){
      union{uint4 v; f16x8 h;}q0, q1;
      q0.v = wlds[nf*64 + l];  q1.v = wlds[(4+nf)*64 + l];
      aA[nf] = MFMA(hA0, q0.h, Z4);  aA[nf] = MFMA(hA1, q1.h, aA[nf]);
      aB[nf] = MFMA(hB0, q0.h, Z4);  aB[nf] = MFMA(hB1, q1.h, aB[nf]);
    }
    // BN2 + lrelu -> per-stream transpose buffers (fp16)
#pragma unroll
    for (int nf=0;nf<4;++nf)
#pragma unroll
      for (int r=0;r<4;++r){
        buf[2*w  ][4*lg+r][16*nf+lr] = h2u((_Float16)lrelu(fmaf(a2v[nf], aA[nf][r], c2v[nf])));
        buf[2*w+1][4*lg+r][16*nf+lr] = h2u((_Float16)lrelu(fmaf(a2v[nf], aB[nf][r], c2v[nf])));
      }
    const f16x8 gA0 = *(const f16x8*)&buf[2*w  ][lr][8*lg];
    const f16x8 gA1 = *(const f16x8*)&buf[2*w  ][lr][32+8*lg];
    const f16x8 gB0 = *(const f16x8*)&buf[2*w+1][lr][8*lg];
    const f16x8 gB1 = *(const f16x8*)&buf[2*w+1][lr][32+8*lg];

    f32x4 cA[4], cB[4];
#pragma unroll
    for (int nf=0;nf<4;++nf){
      union{uint4 v; f16x8 h;}q0, q1;
      q0.v = wlds[512 + nf*64 + l];  q1.v = wlds[512 + (4+nf)*64 + l];
      cA[nf] = MFMA(gA0, q0.h, Z4);  cA[nf] = MFMA(gA1, q1.h, cA[nf]);
      cB[nf] = MFMA(gB0, q0.h, Z4);  cB[nf] = MFMA(gB1, q1.h, cB[nf]);
    }

    // segmax over each node's 16 edges; bias after max; residual
#pragma unroll
    for (int nf=0;nf<4;++nf){
      float mA = fmaxf(fmaxf(cA[nf][0],cA[nf][1]), fmaxf(cA[nf][2],cA[nf][3]));
      mA = fmaxf(mA, __shfl_xor(mA,16,64));
      mA = fmaxf(mA, __shfl_xor(mA,32,64));
      float mB = fmaxf(fmaxf(cB[nf][0],cB[nf][1]), fmaxf(cB[nf][2],cB[nf][3]));
      mB = fmaxf(mB, __shfl_xor(mB,16,64));
      mB = fmaxf(mB, __shfl_xor(mB,32,64));
      if (l < 16){
        const float xA = x[(size_t)nA*64 + nf*16 + l];
        out[(size_t)nA*64 + nf*16 + l] = lrelu(mA + bb[nf] + xA);
        const float xB = x[(size_t)nB*64 + nf*16 + l];
        out[(size_t)nB*64 + nf*16 + l] = lrelu(mB + bb[nf] + xB);
      }
    }
  }
}

extern "C" void kernel_launch(void* const* d_in, const int* in_sizes, int n_in,
                              void* d_out, int out_size, void* d_ws, size_t ws_size,
                              hipStream_t stream) {
  const float* x   = (const float*)d_in[0];
  const int*   ei  = (const int*)d_in[1];
  const float* W1  = (const float*)d_in[2];
  const float* g1  = (const float*)d_in[4];
  const float* be1 = (const float*)d_in[5];
  const float* W2  = (const float*)d_in[6];
  const float* g2  = (const float*)d_in[8];
  const float* be2 = (const float*)d_in[9];
  const float* W3  = (const float*)d_in[10];
  const float* b3  = (const float*)d_in[11];
  float* out = (float*)d_out;

  // ws: coefs 1KB | part1 512KB | part2 512KB | wfb 32KB | U 6.4MB | V 6.4MB
  float*          coefs = (float*)d_ws;
  float*          part1 = (float*)((char*)d_ws + 1024);
  float*          part2 = part1 + (size_t)NB2*128;
  unsigned short* wfb   = (unsigned short*)((char*)part2 + (size_t)NB2*128*4);
  unsigned short* Ub    = (unsigned short*)((char*)wfb + 32768);
  unsigned short* Vb    = Ub + (size_t)N_NODES*64;

  kInit<<<8, 256, 0, stream>>>(W1, W2, W3, wfb);
  kUV<<<(NWT+3)/4, 256, 0, stream>>>(x, (const uint4*)wfb, Ub, Vb);
  kS1<<<NB2, 256, 0, stream>>>(Ub, Vb, ei, part1);
  kFin<<<64, 256, 0, stream>>>(part1, g1, be1, coefs, NB2);
  kScale<<<(N_NODES*8 + 255)/256, 256, 0, stream>>>(Ub, Vb, coefs);
  kS2<<<NB2, 256, 0, stream>>>(Ub, Vb, ei, (const uint4*)wfb, part2);
  kFin<<<64, 256, 0, stream>>>(part2, g2, be2, coefs + 128, NB2);
  kS3<<<NB2, 256, 0, stream>>>(Ub, Vb, ei, (const uint4*)wfb, coefs + 128,
                               b3, x, out);
}

// Round 19
// 107.042 us; speedup vs baseline: 1.1587x; 1.0126x over previous
//
#include <hip/hip_runtime.h>
#include <hip/hip_fp16.h>

#define N_NODES 50000
#define KNN     16
#define NEDGE   (N_NODES*KNN)     // 800000
#define NTILE2  (NEDGE/128)       // 6250 tiles of 128 edges (8 nodes)
#define NWT     (N_NODES/16)      // 3125 wave-tiles for kUV
#define NB2     1024              // grid kS1/kS2/kS3
#define SLOPE   0.01f
#define EPS     1e-5f

typedef __attribute__((ext_vector_type(8))) _Float16 f16x8;
typedef __attribute__((ext_vector_type(4))) float f32x4;

__device__ __forceinline__ unsigned short f2h(float f){
  union{_Float16 h; unsigned short u;} v; v.h = (_Float16)f; return v.u;
}
__device__ __forceinline__ unsigned short h2u(_Float16 h){
  union{_Float16 h; unsigned short u;} v; v.h = h; return v.u;
}
__device__ __forceinline__ f32x4 MFMA(f16x8 a, f16x8 b, f32x4 c){
  return __builtin_amdgcn_mfma_f32_16x16x32_f16(a, b, c, 0, 0, 0);
}
__device__ __forceinline__ float lrelu(float v){ return v>=0.f ? v : SLOPE*v; }

// ---- kUV: per-node U = x(A-B), V = xB (fp16); wf1 self-packed per wave -----
__global__ __launch_bounds__(256) void kUV(const float* __restrict__ x,
    const float* __restrict__ W1, unsigned short* __restrict__ Ub,
    unsigned short* __restrict__ Vb)
{
  const int t = threadIdx.x, w = t>>6, l = t&63, lr = l&15, lg = l>>4;
  const int wt = blockIdx.x*4 + w;
  if (wt >= NWT) return;

  // self-pack wf1 fragments (frags 0..7 = A-B, 8..15 = B); W1 is L1/L2-hot
  f16x8 wfr[16];
#pragma unroll
  for (int f=0;f<16;++f){
    const int ks = f>>2, nf = f&3;
    const int k0 = ks*32 + (lg<<3);
    const int col = nf*16 + lr;
    f16x8 r;
#pragma unroll
    for (int e=0;e<8;++e){
      float v = W1[(size_t)(k0+e)*64 + col];
      if (f < 8) v -= W1[(size_t)(k0+e+64)*64 + col];
      r[e] = (_Float16)v;
    }
    wfr[f] = r;
  }

  const int n0 = wt*16;
  const float* xr = x + (size_t)(n0+lr)*64 + lg*8;
  f16x8 a0, a1;
#pragma unroll
  for (int e=0;e<8;++e){ a0[e] = (_Float16)xr[e]; a1[e] = (_Float16)xr[32+e]; }

  f32x4 aU[4], aV[4];
#pragma unroll
  for (int nf=0;nf<4;++nf){
    aU[nf] = (f32x4){0,0,0,0};
    aU[nf] = MFMA(a0, wfr[nf],    aU[nf]);
    aU[nf] = MFMA(a1, wfr[4+nf],  aU[nf]);
    aV[nf] = (f32x4){0,0,0,0};
    aV[nf] = MFMA(a0, wfr[8+nf],  aV[nf]);
    aV[nf] = MFMA(a1, wfr[12+nf], aV[nf]);
  }
#pragma unroll
  for (int nf=0;nf<4;++nf)
#pragma unroll
    for (int r=0;r<4;++r){
      const size_t o = (size_t)(n0 + 4*lg + r)*64 + 16*nf + lr;
      Ub[o] = f2h(aU[nf][r]);
      Vb[o] = f2h(aV[nf][r]);
    }
}

#define LOADUV(U0,U1,V0,V1, nodeId, srcId)                               \
  {                                                                      \
    const unsigned short* Ur = Ub + (size_t)(nodeId)*64 + lg*8;          \
    const unsigned short* Vr = Vb + (size_t)(srcId)*64  + lg*8;          \
    U0 = *(const f16x8*)(Ur); U1 = *(const f16x8*)(Ur + 32);             \
    V0 = *(const f16x8*)(Vr); V1 = *(const f16x8*)(Vr + 32);             \
  }

// ---- kS1: 2-node ILP; stats of z1 = U + V; blocks 0..3 pack wf2/wf3 --------
__global__ __launch_bounds__(256,4) void kS1(const unsigned short* __restrict__ Ub,
    const unsigned short* __restrict__ Vb, const int* __restrict__ ei,
    const float* __restrict__ W2, const float* __restrict__ W3,
    unsigned short* __restrict__ wf, float* __restrict__ part)
{
  __shared__ float red[4][128];
  const int t = threadIdx.x, w = t>>6, l = t&63, lr = l&15, lg = l>>4;
  const int G = gridDim.x;

  // blocks 0..3 pack the 1024 wf2|wf3 fragment entries (read by kS2/kS3)
  if (blockIdx.x < 4){
    const int idx = blockIdx.x*256 + t;           // 0..1023
    const float* W = (idx < 512) ? W2 : W3;
    const int fi = (idx & 511) >> 6;
    const int ll = idx & 63;
    const int ks = fi >> 2, nf = fi & 3;
    const int k0 = ks*32 + ((ll>>4)<<3);
    const int col = nf*16 + (ll&15);
    unsigned short* o = wf + (size_t)idx*8;
#pragma unroll
    for (int e=0;e<8;++e) o[e] = f2h(W[(size_t)(k0+e)*64 + col]);
  }

  float s[16], q[16];
#pragma unroll
  for (int k=0;k<16;++k){ s[k]=0.f; q[k]=0.f; }

#define ACCST(U0,U1,V0,V1)                                              \
  {                                                                     \
    const f16x8 z0 = U0 + V0, z1 = U1 + V1;                             \
    _Pragma("unroll")                                                   \
    for (int e=0;e<8;++e){ const float zf=(float)z0[e]; s[e]+=zf; q[e]=fmaf(zf,zf,q[e]); } \
    _Pragma("unroll")                                                   \
    for (int e=0;e<8;++e){ const float zf=(float)z1[e]; s[8+e]+=zf; q[8+e]=fmaf(zf,zf,q[8+e]); } \
  }

  int tile = blockIdx.x;
  int srcA = ei[tile*128 + (2*w)*16 + lr];
  int srcB = ei[tile*128 + (2*w+1)*16 + lr];
  for (; tile < NTILE2; tile += G){
    const int nA = tile*8 + 2*w, nB = nA + 1;
    f16x8 uA0,uA1,vA0,vA1, uB0,uB1,vB0,vB1;
    LOADUV(uA0,uA1,vA0,vA1, nA, srcA)
    LOADUV(uB0,uB1,vB0,vB1, nB, srcB)
    const int nt = tile + G;
    if (nt < NTILE2){
      srcA = ei[nt*128 + (2*w)*16 + lr];
      srcB = ei[nt*128 + (2*w+1)*16 + lr];
    }
    ACCST(uA0,uA1,vA0,vA1)
    ACCST(uB0,uB1,vB0,vB1)
  }

#pragma unroll
  for (int k=0;k<16;++k){
    float a=s[k]; a+=__shfl_xor(a,1,64); a+=__shfl_xor(a,2,64);
    a+=__shfl_xor(a,4,64); a+=__shfl_xor(a,8,64); s[k]=a;
    float b=q[k]; b+=__shfl_xor(b,1,64); b+=__shfl_xor(b,2,64);
    b+=__shfl_xor(b,4,64); b+=__shfl_xor(b,8,64); q[k]=b;
  }
  if (lr == 0){
#pragma unroll
    for (int e=0;e<8;++e){
      red[w][8*lg+e]    = s[e];
      red[w][32+8*lg+e] = s[8+e];
      red[w][64+8*lg+e] = q[e];
      red[w][96+8*lg+e] = q[8+e];
    }
  }
  __syncthreads();
  if (t < 128)
    part[(size_t)t*NB2 + blockIdx.x] = red[0][t]+red[1][t]+red[2][t]+red[3][t];
}

// ---- kFin: 64 blocks, block c reduces sum/sq rows over nb entries ----------
__global__ __launch_bounds__(256) void kFin(const float* __restrict__ part,
    const float* __restrict__ g, const float* __restrict__ be,
    float* __restrict__ coefs, int nb)
{
  __shared__ float rs[256], rq[256];
  const int c = blockIdx.x, t = threadIdx.x;
  const float* ps = part + (size_t)c*nb;
  const float* pq = part + (size_t)(64+c)*nb;
  float s = 0.f, q = 0.f;
  for (int i=t; i<nb; i+=256){ s += ps[i]; q += pq[i]; }
  rs[t]=s; rq[t]=q;
  __syncthreads();
#pragma unroll
  for (int off=128; off>0; off>>=1){
    if (t < off){ rs[t]+=rs[t+off]; rq[t]+=rq[t+off]; }
    __syncthreads();
  }
  if (t==0){
    const float inv  = 1.0f/(float)NEDGE;
    const float mean = rs[0]*inv;
    const float var  = rq[0]*inv - mean*mean;
    const float a    = g[c]*rsqrtf(var + EPS);
    coefs[c]      = a;
    coefs[64 + c] = be[c] - mean*a;
  }
}

// load packed-fp16 BN1 coefs for this lane's k-blocks
#define LOAD_C1                                                         \
  f16x8 A1a, A1b, C1a, C1b;                                             \
  {                                                                     \
    const int kb = lg*8;                                                \
    _Pragma("unroll")                                                   \
    for (int e=0;e<8;++e){                                              \
      A1a[e] = (_Float16)coefs1[kb+e];    A1b[e] = (_Float16)coefs1[32+kb+e]; \
      C1a[e] = (_Float16)coefs1[64+kb+e]; C1b[e] = (_Float16)coefs1[96+kb+e]; \
    }                                                                   \
  }

// h1 = lrelu(a1*(U+V)+c1), fully packed fp16
#define H1F(h0f, h1f, U0,U1,V0,V1)                                      \
  f16x8 h0f, h1f;                                                       \
  {                                                                     \
    const f16x8 t0 = (U0 + V0) * A1a + C1a;                             \
    const f16x8 t1 = (U1 + V1) * A1b + C1b;                             \
    h0f = __builtin_elementwise_max(t0, t0 * (_Float16)0.01f);          \
    h1f = __builtin_elementwise_max(t1, t1 * (_Float16)0.01f);          \
  }

// ---- kS2: 2-node ILP; h1 = lrelu(bn1(U+V)); z2 = h1@W2; stats2 -------------
__global__ __launch_bounds__(256,4) void kS2(const unsigned short* __restrict__ Ub,
    const unsigned short* __restrict__ Vb, const int* __restrict__ ei,
    const uint4* __restrict__ wfg, const float* __restrict__ coefs1,
    float* __restrict__ part)
{
  __shared__ uint4 wlds[512];          // wf2 table, 8 KB
  __shared__ float red[4][128];
  const int t = threadIdx.x, w = t>>6, l = t&63, lr = l&15, lg = l>>4;
  const int G = gridDim.x;
  const f32x4 Z4 = (f32x4){0.f,0.f,0.f,0.f};

  for (int i=t; i<512; i+=256) wlds[i] = wfg[i];
  __syncthreads();
  LOAD_C1

  float sumP[4] = {0,0,0,0}, sqP[4] = {0,0,0,0};

  int tile = blockIdx.x;
  int srcA = ei[tile*128 + (2*w)*16 + lr];
  int srcB = ei[tile*128 + (2*w+1)*16 + lr];
  for (; tile < NTILE2; tile += G){
    const int nA = tile*8 + 2*w, nB = nA + 1;
    f16x8 uA0,uA1,vA0,vA1, uB0,uB1,vB0,vB1;
    LOADUV(uA0,uA1,vA0,vA1, nA, srcA)
    LOADUV(uB0,uB1,vB0,vB1, nB, srcB)
    const int nt = tile + G;
    if (nt < NTILE2){
      srcA = ei[nt*128 + (2*w)*16 + lr];
      srcB = ei[nt*128 + (2*w+1)*16 + lr];
    }

    H1F(hA0, hA1, uA0,uA1,vA0,vA1)
    H1F(hB0, hB1, uB0,uB1,vB0,vB1)

    f32x4 aA[4], aB[4];
#pragma unroll
    for (int nf=0;nf<4;++nf){
      union{uint4 v; f16x8 h;}q0, q1;
      q0.v = wlds[nf*64 + l];  q1.v = wlds[(4+nf)*64 + l];
      aA[nf] = MFMA(hA0, q0.h, Z4);  aA[nf] = MFMA(hA1, q1.h, aA[nf]);
      aB[nf] = MFMA(hB0, q0.h, Z4);  aB[nf] = MFMA(hB1, q1.h, aB[nf]);
    }
#pragma unroll
    for (int nf=0;nf<4;++nf)
#pragma unroll
      for (int r=0;r<4;++r){
        const float v0 = aA[nf][r], v1 = aB[nf][r];
        sumP[nf] += v0 + v1;
        sqP[nf] = fmaf(v0,v0,sqP[nf]);
        sqP[nf] = fmaf(v1,v1,sqP[nf]);
      }
  }

#pragma unroll
  for (int nf=0;nf<4;++nf){
    float s = sumP[nf], q = sqP[nf];
    s += __shfl_xor(s,16,64); s += __shfl_xor(s,32,64);
    q += __shfl_xor(q,16,64); q += __shfl_xor(q,32,64);
    if (l < 16){ red[w][nf*16+l] = s; red[w][64+nf*16+l] = q; }
  }
  __syncthreads();
  if (t < 128)
    part[(size_t)t*NB2 + blockIdx.x] = red[0][t]+red[1][t]+red[2][t]+red[3][t];
}

// ---- kS3: 2-node ILP; h1 -> z2 -> BN2+lrelu -> z3 -> segmax -> out ---------
__global__ __launch_bounds__(256,4) void kS3(const unsigned short* __restrict__ Ub,
    const unsigned short* __restrict__ Vb, const int* __restrict__ ei,
    const uint4* __restrict__ wfg, const float* __restrict__ coefs1,
    const float* __restrict__ coefs2, const float* __restrict__ b3,
    const float* __restrict__ x, float* __restrict__ out)
{
  __shared__ uint4 wlds[1024];                              // wf2|wf3, 16 KB
  __shared__ __align__(16) unsigned short buf[8][16][72];   // per-stream, 18 KB
  const int t = threadIdx.x, w = t>>6, l = t&63, lr = l&15, lg = l>>4;
  const int G = gridDim.x;
  const f32x4 Z4 = (f32x4){0.f,0.f,0.f,0.f};

  for (int i=t; i<1024; i+=256) wlds[i] = wfg[i];
  __syncthreads();
  LOAD_C1

  float a2v[4], c2v[4], bb[4];
#pragma unroll
  for (int nf=0;nf<4;++nf){
    a2v[nf]=coefs2[nf*16+lr]; c2v[nf]=coefs2[64+nf*16+lr];
    bb[nf] = b3[nf*16+lr];
  }

  int tile = blockIdx.x;
  int srcA = ei[tile*128 + (2*w)*16 + lr];
  int srcB = ei[tile*128 + (2*w+1)*16 + lr];
  for (; tile < NTILE2; tile += G){
    const int nA = tile*8 + 2*w, nB = nA + 1;
    f16x8 uA0,uA1,vA0,vA1, uB0,uB1,vB0,vB1;
    LOADUV(uA0,uA1,vA0,vA1, nA, srcA)
    LOADUV(uB0,uB1,vB0,vB1, nB, srcB)
    const int nt = tile + G;
    if (nt < NTILE2){
      srcA = ei[nt*128 + (2*w)*16 + lr];
      srcB = ei[nt*128 + (2*w+1)*16 + lr];
    }

    H1F(hA0, hA1, uA0,uA1,vA0,vA1)
    H1F(hB0, hB1, uB0,uB1,vB0,vB1)

    // GEMM2 (unswapped): D = z2[edge 4lg+r][ch 16nf+lr]; B shared across streams
    f32x4 aA[4], aB[4];
#pragma unroll
    for (int nf=0;nf<4;++nf){
      union{uint4 v; f16x8 h;}q0, q1;
      q0.v = wlds[nf*64 + l];  q1.v = wlds[(4+nf)*64 + l];
      aA[nf] = MFMA(hA0, q0.h, Z4);  aA[nf] = MFMA(hA1, q1.h, aA[nf]);
      aB[nf] = MFMA(hB0, q0.h, Z4);  aB[nf] = MFMA(hB1, q1.h, aB[nf]);
    }
    // BN2 + lrelu -> per-stream transpose buffers (fp16)
#pragma unroll
    for (int nf=0;nf<4;++nf)
#pragma unroll
      for (int r=0;r<4;++r){
        buf[2*w  ][4*lg+r][16*nf+lr] = h2u((_Float16)lrelu(fmaf(a2v[nf], aA[nf][r], c2v[nf])));
        buf[2*w+1][4*lg+r][16*nf+lr] = h2u((_Float16)lrelu(fmaf(a2v[nf], aB[nf][r], c2v[nf])));
      }
    const f16x8 gA0 = *(const f16x8*)&buf[2*w  ][lr][8*lg];
    const f16x8 gA1 = *(const f16x8*)&buf[2*w  ][lr][32+8*lg];
    const f16x8 gB0 = *(const f16x8*)&buf[2*w+1][lr][8*lg];
    const f16x8 gB1 = *(const f16x8*)&buf[2*w+1][lr][32+8*lg];

    f32x4 cA[4], cB[4];
#pragma unroll
    for (int nf=0;nf<4;++nf){
      union{uint4 v; f16x8 h;}q0, q1;
      q0.v = wlds[512 + nf*64 + l];  q1.v = wlds[512 + (4+nf)*64 + l];
      cA[nf] = MFMA(gA0, q0.h, Z4);  cA[nf] = MFMA(gA1, q1.h, cA[nf]);
      cB[nf] = MFMA(gB0, q0.h, Z4);  cB[nf] = MFMA(gB1, q1.h, cB[nf]);
    }

    // segmax over each node's 16 edges; bias after max; residual
#pragma unroll
    for (int nf=0;nf<4;++nf){
      float mA = fmaxf(fmaxf(cA[nf][0],cA[nf][1]), fmaxf(cA[nf][2],cA[nf][3]));
      mA = fmaxf(mA, __shfl_xor(mA,16,64));
      mA = fmaxf(mA, __shfl_xor(mA,32,64));
      float mB = fmaxf(fmaxf(cB[nf][0],cB[nf][1]), fmaxf(cB[nf][2],cB[nf][3]));
      mB = fmaxf(mB, __shfl_xor(mB,16,64));
      mB = fmaxf(mB, __shfl_xor(mB,32,64));
      if (l < 16){
        const float xA = x[(size_t)nA*64 + nf*16 + l];
        out[(size_t)nA*64 + nf*16 + l] = lrelu(mA + bb[nf] + xA);
        const float xB = x[(size_t)nB*64 + nf*16 + l];
        out[(size_t)nB*64 + nf*16 + l] = lrelu(mB + bb[nf] + xB);
      }
    }
  }
}

extern "C" void kernel_launch(void* const* d_in, const int* in_sizes, int n_in,
                              void* d_out, int out_size, void* d_ws, size_t ws_size,
                              hipStream_t stream) {
  const float* x   = (const float*)d_in[0];
  const int*   ei  = (const int*)d_in[1];
  const float* W1  = (const float*)d_in[2];
  const float* g1  = (const float*)d_in[4];
  const float* be1 = (const float*)d_in[5];
  const float* W2  = (const float*)d_in[6];
  const float* g2  = (const float*)d_in[8];
  const float* be2 = (const float*)d_in[9];
  const float* W3  = (const float*)d_in[10];
  const float* b3  = (const float*)d_in[11];
  float* out = (float*)d_out;

  // ws: coefs 1KB | part1 512KB | part2 512KB | wfb 16KB | U 6.4MB | V 6.4MB
  float*          coefs = (float*)d_ws;
  float*          part1 = (float*)((char*)d_ws + 1024);
  float*          part2 = part1 + (size_t)NB2*128;
  unsigned short* wfb   = (unsigned short*)((char*)part2 + (size_t)NB2*128*4);
  unsigned short* Ub    = (unsigned short*)((char*)wfb + 16384);
  unsigned short* Vb    = Ub + (size_t)N_NODES*64;

  kUV<<<(NWT+3)/4, 256, 0, stream>>>(x, W1, Ub, Vb);
  kS1<<<NB2, 256, 0, stream>>>(Ub, Vb, ei, W2, W3, wfb, part1);
  kFin<<<64, 256, 0, stream>>>(part1, g1, be1, coefs, NB2);
  kS2<<<NB2, 256, 0, stream>>>(Ub, Vb, ei, (const uint4*)wfb, coefs, part2);
  kFin<<<64, 256, 0, stream>>>(part2, g2, be2, coefs + 128, NB2);
  kS3<<<NB2, 256, 0, stream>>>(Ub, Vb, ei, (const uint4*)wfb, coefs,
                               coefs + 128, b3, x, out);
}

// Round 20
// 98.949 us; speedup vs baseline: 1.2535x; 1.0818x over previous
//
#include <hip/hip_runtime.h>
#include <hip/hip_fp16.h>

#define N_NODES 50000
#define KNN     16
#define NEDGE   (N_NODES*KNN)     // 800000
#define NTILE2  (NEDGE/128)       // 6250 tiles of 128 edges (8 nodes)
#define NWT     (N_NODES/16)      // 3125 wave-tiles for kUV
#define NB2     1024              // grid kS1/kS2/kS3
#define SLOPE   0.01f
#define EPS     1e-5f

typedef __attribute__((ext_vector_type(8))) _Float16 f16x8;
typedef __attribute__((ext_vector_type(4))) float f32x4;

__device__ __forceinline__ unsigned short f2h(float f){
  union{_Float16 h; unsigned short u;} v; v.h = (_Float16)f; return v.u;
}
__device__ __forceinline__ unsigned short h2u(_Float16 h){
  union{_Float16 h; unsigned short u;} v; v.h = h; return v.u;
}
__device__ __forceinline__ f32x4 MFMA(f16x8 a, f16x8 b, f32x4 c){
  return __builtin_amdgcn_mfma_f32_16x16x32_f16(a, b, c, 0, 0, 0);
}
__device__ __forceinline__ float lrelu(float v){ return v>=0.f ? v : SLOPE*v; }

// ---- kUV: per-node U = x(A-B), V = xB (fp16); wf1 self-packed per wave -----
__global__ __launch_bounds__(256) void kUV(const float* __restrict__ x,
    const float* __restrict__ W1, unsigned short* __restrict__ Ub,
    unsigned short* __restrict__ Vb)
{
  const int t = threadIdx.x, w = t>>6, l = t&63, lr = l&15, lg = l>>4;
  const int wt = blockIdx.x*4 + w;
  if (wt >= NWT) return;

  // self-pack wf1 fragments (frags 0..7 = A-B, 8..15 = B); W1 is L1/L2-hot
  f16x8 wfr[16];
#pragma unroll
  for (int f=0;f<16;++f){
    const int ks = f>>2, nf = f&3;
    const int k0 = ks*32 + (lg<<3);
    const int col = nf*16 + lr;
    f16x8 r;
#pragma unroll
    for (int e=0;e<8;++e){
      float v = W1[(size_t)(k0+e)*64 + col];
      if (f < 8) v -= W1[(size_t)(k0+e+64)*64 + col];
      r[e] = (_Float16)v;
    }
    wfr[f] = r;
  }

  const int n0 = wt*16;
  const float* xr = x + (size_t)(n0+lr)*64 + lg*8;
  f16x8 a0, a1;
#pragma unroll
  for (int e=0;e<8;++e){ a0[e] = (_Float16)xr[e]; a1[e] = (_Float16)xr[32+e]; }

  f32x4 aU[4], aV[4];
#pragma unroll
  for (int nf=0;nf<4;++nf){
    aU[nf] = (f32x4){0,0,0,0};
    aU[nf] = MFMA(a0, wfr[nf],    aU[nf]);
    aU[nf] = MFMA(a1, wfr[4+nf],  aU[nf]);
    aV[nf] = (f32x4){0,0,0,0};
    aV[nf] = MFMA(a0, wfr[8+nf],  aV[nf]);
    aV[nf] = MFMA(a1, wfr[12+nf], aV[nf]);
  }
#pragma unroll
  for (int nf=0;nf<4;++nf)
#pragma unroll
    for (int r=0;r<4;++r){
      const size_t o = (size_t)(n0 + 4*lg + r)*64 + 16*nf + lr;
      Ub[o] = f2h(aU[nf][r]);
      Vb[o] = f2h(aV[nf][r]);
    }
}

#define LOADUV(U0,U1,V0,V1, nodeId, srcId)                               \
  {                                                                      \
    const unsigned short* Ur = Ub + (size_t)(nodeId)*64 + lg*8;          \
    const unsigned short* Vr = Vb + (size_t)(srcId)*64  + lg*8;          \
    U0 = *(const f16x8*)(Ur); U1 = *(const f16x8*)(Ur + 32);             \
    V0 = *(const f16x8*)(Vr); V1 = *(const f16x8*)(Vr + 32);             \
  }

// ---- kS1: 2-node ILP; stats of z1 = U + V; blocks 0..3 pack wf2/wf3 --------
__global__ __launch_bounds__(256,4) void kS1(const unsigned short* __restrict__ Ub,
    const unsigned short* __restrict__ Vb, const int* __restrict__ ei,
    const float* __restrict__ W2, const float* __restrict__ W3,
    unsigned short* __restrict__ wf, float* __restrict__ part)
{
  __shared__ float red[4][128];
  const int t = threadIdx.x, w = t>>6, l = t&63, lr = l&15, lg = l>>4;
  const int G = gridDim.x;

  // blocks 0..3 pack the 1024 wf2|wf3 fragment entries (read by kS2/kS3)
  if (blockIdx.x < 4){
    const int idx = blockIdx.x*256 + t;           // 0..1023
    const float* W = (idx < 512) ? W2 : W3;
    const int fi = (idx & 511) >> 6;
    const int ll = idx & 63;
    const int ks = fi >> 2, nf = fi & 3;
    const int k0 = ks*32 + ((ll>>4)<<3);
    const int col = nf*16 + (ll&15);
    unsigned short* o = wf + (size_t)idx*8;
#pragma unroll
    for (int e=0;e<8;++e) o[e] = f2h(W[(size_t)(k0+e)*64 + col]);
  }

  float s[16], q[16];
#pragma unroll
  for (int k=0;k<16;++k){ s[k]=0.f; q[k]=0.f; }

#define ACCST(U0,U1,V0,V1)                                              \
  {                                                                     \
    const f16x8 z0 = U0 + V0, z1 = U1 + V1;                             \
    _Pragma("unroll")                                                   \
    for (int e=0;e<8;++e){ const float zf=(float)z0[e]; s[e]+=zf; q[e]=fmaf(zf,zf,q[e]); } \
    _Pragma("unroll")                                                   \
    for (int e=0;e<8;++e){ const float zf=(float)z1[e]; s[8+e]+=zf; q[8+e]=fmaf(zf,zf,q[8+e]); } \
  }

  int tile = blockIdx.x;
  int srcA = ei[tile*128 + (2*w)*16 + lr];
  int srcB = ei[tile*128 + (2*w+1)*16 + lr];
  for (; tile < NTILE2; tile += G){
    const int nA = tile*8 + 2*w, nB = nA + 1;
    f16x8 uA0,uA1,vA0,vA1, uB0,uB1,vB0,vB1;
    LOADUV(uA0,uA1,vA0,vA1, nA, srcA)
    LOADUV(uB0,uB1,vB0,vB1, nB, srcB)
    const int nt = tile + G;
    if (nt < NTILE2){
      srcA = ei[nt*128 + (2*w)*16 + lr];
      srcB = ei[nt*128 + (2*w+1)*16 + lr];
    }
    ACCST(uA0,uA1,vA0,vA1)
    ACCST(uB0,uB1,vB0,vB1)
  }

#pragma unroll
  for (int k=0;k<16;++k){
    float a=s[k]; a+=__shfl_xor(a,1,64); a+=__shfl_xor(a,2,64);
    a+=__shfl_xor(a,4,64); a+=__shfl_xor(a,8,64); s[k]=a;
    float b=q[k]; b+=__shfl_xor(b,1,64); b+=__shfl_xor(b,2,64);
    b+=__shfl_xor(b,4,64); b+=__shfl_xor(b,8,64); q[k]=b;
  }
  if (lr == 0){
#pragma unroll
    for (int e=0;e<8;++e){
      red[w][8*lg+e]    = s[e];
      red[w][32+8*lg+e] = s[8+e];
      red[w][64+8*lg+e] = q[e];
      red[w][96+8*lg+e] = q[8+e];
    }
  }
  __syncthreads();
  if (t < 128)
    part[(size_t)t*NB2 + blockIdx.x] = red[0][t]+red[1][t]+red[2][t]+red[3][t];
}

// ---- kFin: 64 blocks; writes f32 coefs AND packed fp16 coefs ---------------
__global__ __launch_bounds__(256) void kFin(const float* __restrict__ part,
    const float* __restrict__ g, const float* __restrict__ be,
    float* __restrict__ coefs, unsigned short* __restrict__ coefsH, int nb)
{
  __shared__ float rs[256], rq[256];
  const int c = blockIdx.x, t = threadIdx.x;
  const float* ps = part + (size_t)c*nb;
  const float* pq = part + (size_t)(64+c)*nb;
  float s = 0.f, q = 0.f;
  for (int i=t; i<nb; i+=256){ s += ps[i]; q += pq[i]; }
  rs[t]=s; rq[t]=q;
  __syncthreads();
#pragma unroll
  for (int off=128; off>0; off>>=1){
    if (t < off){ rs[t]+=rs[t+off]; rq[t]+=rq[t+off]; }
    __syncthreads();
  }
  if (t==0){
    const float inv  = 1.0f/(float)NEDGE;
    const float mean = rs[0]*inv;
    const float var  = rq[0]*inv - mean*mean;
    const float a    = g[c]*rsqrtf(var + EPS);
    const float cc   = be[c] - mean*a;
    coefs[c]       = a;
    coefs[64 + c]  = cc;
    coefsH[c]      = f2h(a);
    coefsH[64 + c] = f2h(cc);
  }
}

// load packed-fp16 BN1 coefs as FOUR b64 vector loads (no insert-element)
#define LOAD_C1                                                         \
  f16x8 A1a, A1b, C1a, C1b;                                             \
  {                                                                     \
    const int kb = lg*8;                                                \
    A1a = *(const f16x8*)(coefsH1 + kb);                                \
    A1b = *(const f16x8*)(coefsH1 + 32 + kb);                           \
    C1a = *(const f16x8*)(coefsH1 + 64 + kb);                           \
    C1b = *(const f16x8*)(coefsH1 + 96 + kb);                           \
  }

// h1 = lrelu(a1*(U+V)+c1), fully packed fp16
#define H1F(h0f, h1f, U0,U1,V0,V1)                                      \
  f16x8 h0f, h1f;                                                       \
  {                                                                     \
    const f16x8 t0 = (U0 + V0) * A1a + C1a;                             \
    const f16x8 t1 = (U1 + V1) * A1b + C1b;                             \
    h0f = __builtin_elementwise_max(t0, t0 * (_Float16)0.01f);          \
    h1f = __builtin_elementwise_max(t1, t1 * (_Float16)0.01f);          \
  }

// ---- kS2: 2-node ILP; h1 = lrelu(bn1(U+V)); z2 = h1@W2; stats2 -------------
__global__ __launch_bounds__(256,4) void kS2(const unsigned short* __restrict__ Ub,
    const unsigned short* __restrict__ Vb, const int* __restrict__ ei,
    const uint4* __restrict__ wfg, const unsigned short* __restrict__ coefsH1,
    float* __restrict__ part)
{
  __shared__ uint4 wlds[512];          // wf2 table, 8 KB
  __shared__ float red[4][128];
  const int t = threadIdx.x, w = t>>6, l = t&63, lr = l&15, lg = l>>4;
  const int G = gridDim.x;
  const f32x4 Z4 = (f32x4){0.f,0.f,0.f,0.f};

  for (int i=t; i<512; i+=256) wlds[i] = wfg[i];
  __syncthreads();
  LOAD_C1

  float sumP[4] = {0,0,0,0}, sqP[4] = {0,0,0,0};

  int tile = blockIdx.x;
  int srcA = ei[tile*128 + (2*w)*16 + lr];
  int srcB = ei[tile*128 + (2*w+1)*16 + lr];
  for (; tile < NTILE2; tile += G){
    const int nA = tile*8 + 2*w, nB = nA + 1;
    f16x8 uA0,uA1,vA0,vA1, uB0,uB1,vB0,vB1;
    LOADUV(uA0,uA1,vA0,vA1, nA, srcA)
    LOADUV(uB0,uB1,vB0,vB1, nB, srcB)
    const int nt = tile + G;
    if (nt < NTILE2){
      srcA = ei[nt*128 + (2*w)*16 + lr];
      srcB = ei[nt*128 + (2*w+1)*16 + lr];
    }

    H1F(hA0, hA1, uA0,uA1,vA0,vA1)
    H1F(hB0, hB1, uB0,uB1,vB0,vB1)

    f32x4 aA[4], aB[4];
#pragma unroll
    for (int nf=0;nf<4;++nf){
      union{uint4 v; f16x8 h;}q0, q1;
      q0.v = wlds[nf*64 + l];  q1.v = wlds[(4+nf)*64 + l];
      aA[nf] = MFMA(hA0, q0.h, Z4);  aA[nf] = MFMA(hA1, q1.h, aA[nf]);
      aB[nf] = MFMA(hB0, q0.h, Z4);  aB[nf] = MFMA(hB1, q1.h, aB[nf]);
    }
#pragma unroll
    for (int nf=0;nf<4;++nf)
#pragma unroll
      for (int r=0;r<4;++r){
        const float v0 = aA[nf][r], v1 = aB[nf][r];
        sumP[nf] += v0 + v1;
        sqP[nf] = fmaf(v0,v0,sqP[nf]);
        sqP[nf] = fmaf(v1,v1,sqP[nf]);
      }
  }

#pragma unroll
  for (int nf=0;nf<4;++nf){
    float s = sumP[nf], q = sqP[nf];
    s += __shfl_xor(s,16,64); s += __shfl_xor(s,32,64);
    q += __shfl_xor(q,16,64); q += __shfl_xor(q,32,64);
    if (l < 16){ red[w][nf*16+l] = s; red[w][64+nf*16+l] = q; }
  }
  __syncthreads();
  if (t < 128)
    part[(size_t)t*NB2 + blockIdx.x] = red[0][t]+red[1][t]+red[2][t]+red[3][t];
}

// ---- kS3: 2-node ILP; h1 -> z2 -> BN2+lrelu -> z3 -> segmax -> out ---------
__global__ __launch_bounds__(256,4) void kS3(const unsigned short* __restrict__ Ub,
    const unsigned short* __restrict__ Vb, const int* __restrict__ ei,
    const uint4* __restrict__ wfg, const unsigned short* __restrict__ coefsH1,
    const float* __restrict__ coefs2, const float* __restrict__ b3,
    const float* __restrict__ x, float* __restrict__ out)
{
  __shared__ uint4 wlds[1024];                              // wf2|wf3, 16 KB
  __shared__ __align__(16) unsigned short buf[8][16][72];   // per-stream, 18 KB
  const int t = threadIdx.x, w = t>>6, l = t&63, lr = l&15, lg = l>>4;
  const int G = gridDim.x;
  const f32x4 Z4 = (f32x4){0.f,0.f,0.f,0.f};

  for (int i=t; i<1024; i+=256) wlds[i] = wfg[i];
  __syncthreads();
  LOAD_C1

  float a2v[4], c2v[4], bb[4];
#pragma unroll
  for (int nf=0;nf<4;++nf){
    a2v[nf]=coefs2[nf*16+lr]; c2v[nf]=coefs2[64+nf*16+lr];
    bb[nf] = b3[nf*16+lr];
  }

  int tile = blockIdx.x;
  int srcA = ei[tile*128 + (2*w)*16 + lr];
  int srcB = ei[tile*128 + (2*w+1)*16 + lr];
  for (; tile < NTILE2; tile += G){
    const int nA = tile*8 + 2*w, nB = nA + 1;
    f16x8 uA0,uA1,vA0,vA1, uB0,uB1,vB0,vB1;
    LOADUV(uA0,uA1,vA0,vA1, nA, srcA)
    LOADUV(uB0,uB1,vB0,vB1, nB, srcB)
    const int nt = tile + G;
    if (nt < NTILE2){
      srcA = ei[nt*128 + (2*w)*16 + lr];
      srcB = ei[nt*128 + (2*w+1)*16 + lr];
    }

    H1F(hA0, hA1, uA0,uA1,vA0,vA1)
    H1F(hB0, hB1, uB0,uB1,vB0,vB1)

    // GEMM2 (unswapped): D = z2[edge 4lg+r][ch 16nf+lr]; B shared across streams
    f32x4 aA[4], aB[4];
#pragma unroll
    for (int nf=0;nf<4;++nf){
      union{uint4 v; f16x8 h;}q0, q1;
      q0.v = wlds[nf*64 + l];  q1.v = wlds[(4+nf)*64 + l];
      aA[nf] = MFMA(hA0, q0.h, Z4);  aA[nf] = MFMA(hA1, q1.h, aA[nf]);
      aB[nf] = MFMA(hB0, q0.h, Z4);  aB[nf] = MFMA(hB1, q1.h, aB[nf]);
    }
    // BN2 + lrelu -> per-stream transpose buffers (fp16)
#pragma unroll
    for (int nf=0;nf<4;++nf)
#pragma unroll
      for (int r=0;r<4;++r){
        buf[2*w  ][4*lg+r][16*nf+lr] = h2u((_Float16)lrelu(fmaf(a2v[nf], aA[nf][r], c2v[nf])));
        buf[2*w+1][4*lg+r][16*nf+lr] = h2u((_Float16)lrelu(fmaf(a2v[nf], aB[nf][r], c2v[nf])));
      }
    const f16x8 gA0 = *(const f16x8*)&buf[2*w  ][lr][8*lg];
    const f16x8 gA1 = *(const f16x8*)&buf[2*w  ][lr][32+8*lg];
    const f16x8 gB0 = *(const f16x8*)&buf[2*w+1][lr][8*lg];
    const f16x8 gB1 = *(const f16x8*)&buf[2*w+1][lr][32+8*lg];

    f32x4 cA[4], cB[4];
#pragma unroll
    for (int nf=0;nf<4;++nf){
      union{uint4 v; f16x8 h;}q0, q1;
      q0.v = wlds[512 + nf*64 + l];  q1.v = wlds[512 + (4+nf)*64 + l];
      cA[nf] = MFMA(gA0, q0.h, Z4);  cA[nf] = MFMA(gA1, q1.h, cA[nf]);
      cB[nf] = MFMA(gB0, q0.h, Z4);  cB[nf] = MFMA(gB1, q1.h, cB[nf]);
    }

    // segmax over each node's 16 edges; bias after max; residual
#pragma unroll
    for (int nf=0;nf<4;++nf){
      float mA = fmaxf(fmaxf(cA[nf][0],cA[nf][1]), fmaxf(cA[nf][2],cA[nf][3]));
      mA = fmaxf(mA, __shfl_xor(mA,16,64));
      mA = fmaxf(mA, __shfl_xor(mA,32,64));
      float mB = fmaxf(fmaxf(cB[nf][0],cB[nf][1]), fmaxf(cB[nf][2],cB[nf][3]));
      mB = fmaxf(mB, __shfl_xor(mB,16,64));
      mB = fmaxf(mB, __shfl_xor(mB,32,64));
      if (l < 16){
        const float xA = x[(size_t)nA*64 + nf*16 + l];
        out[(size_t)nA*64 + nf*16 + l] = lrelu(mA + bb[nf] + xA);
        const float xB = x[(size_t)nB*64 + nf*16 + l];
        out[(size_t)nB*64 + nf*16 + l] = lrelu(mB + bb[nf] + xB);
      }
    }
  }
}

extern "C" void kernel_launch(void* const* d_in, const int* in_sizes, int n_in,
                              void* d_out, int out_size, void* d_ws, size_t ws_size,
                              hipStream_t stream) {
  const float* x   = (const float*)d_in[0];
  const int*   ei  = (const int*)d_in[1];
  const float* W1  = (const float*)d_in[2];
  const float* g1  = (const float*)d_in[4];
  const float* be1 = (const float*)d_in[5];
  const float* W2  = (const float*)d_in[6];
  const float* g2  = (const float*)d_in[8];
  const float* be2 = (const float*)d_in[9];
  const float* W3  = (const float*)d_in[10];
  const float* b3  = (const float*)d_in[11];
  float* out = (float*)d_out;

  // ws: coefs 1KB | coefsH 1KB | part1 512KB | part2 512KB | wfb 16KB | U | V
  float*          coefs  = (float*)d_ws;
  unsigned short* coefsH = (unsigned short*)((char*)d_ws + 1024);
  float*          part1  = (float*)((char*)d_ws + 2048);
  float*          part2  = part1 + (size_t)NB2*128;
  unsigned short* wfb    = (unsigned short*)((char*)part2 + (size_t)NB2*128*4);
  unsigned short* Ub     = (unsigned short*)((char*)wfb + 16384);
  unsigned short* Vb     = Ub + (size_t)N_NODES*64;

  kUV<<<(NWT+3)/4, 256, 0, stream>>>(x, W1, Ub, Vb);
  kS1<<<NB2, 256, 0, stream>>>(Ub, Vb, ei, W2, W3, wfb, part1);
  kFin<<<64, 256, 0, stream>>>(part1, g1, be1, coefs, coefsH, NB2);
  kS2<<<NB2, 256, 0, stream>>>(Ub, Vb, ei, (const uint4*)wfb, coefsH, part2);
  kFin<<<64, 256, 0, stream>>>(part2, g2, be2, coefs + 128, coefsH + 128, NB2);
  kS3<<<NB2, 256, 0, stream>>>(Ub, Vb, ei, (const uint4*)wfb, coefsH,
                               coefs + 128, b3, x, out);
}